// Round 1
// baseline (1013.943 us; speedup 1.0000x reference)
//
#include <hip/hip_runtime.h>

#define N_NODES 50000
#define N_EDGES 1600000
#define FDIM    128
#define C_OUT   10

// ---------------------------------------------------------------- init
__global__ void k_init(float* __restrict__ deg, int* __restrict__ cnt) {
    int i = blockIdx.x * 256 + threadIdx.x;
    if (i < N_NODES) { deg[i] = 1.0f; cnt[i] = 0; }   // self-loop weight 1 pre-added
}

// ------------------------------------------------- degree + dst histogram
__global__ void k_deg_hist(const int* __restrict__ src, const int* __restrict__ dst,
                           const float* __restrict__ w,
                           float* __restrict__ deg, int* __restrict__ cnt) {
    int e = blockIdx.x * 256 + threadIdx.x;
    if (e < N_EDGES) {
        int d = dst[e];
        atomicAdd(&deg[d], w[e]);
        atomicAdd(&cnt[d], 1);
    }
}

// ---------------------------------------- single-block exclusive scan + dinv
__global__ __launch_bounds__(1024)
void k_scan(const float* __restrict__ deg, float* __restrict__ dinv,
            int* __restrict__ cnt_cursor, int* __restrict__ rowptr) {
    __shared__ int sums[1024];
    int t = threadIdx.x;
    const int CH = (N_NODES + 1023) / 1024;     // 49
    int lo = t * CH, hi = min(lo + CH, N_NODES);
    int s = 0;
    for (int i = lo; i < hi; ++i) {
        s += cnt_cursor[i];
        float dg = deg[i];
        dinv[i] = dg > 0.0f ? rsqrtf(dg) : 0.0f;
    }
    sums[t] = s;
    __syncthreads();
    for (int off = 1; off < 1024; off <<= 1) {   // Hillis-Steele inclusive scan
        int v = (t >= off) ? sums[t - off] : 0;
        __syncthreads();
        sums[t] += v;
        __syncthreads();
    }
    int run = sums[t] - s;                       // exclusive prefix for this chunk
    for (int i = lo; i < hi; ++i) {
        int c = cnt_cursor[i];
        rowptr[i] = run;
        cnt_cursor[i] = run;                     // cursor starts at row offset
        run += c;
    }
    if (t == 0) rowptr[N_NODES] = N_EDGES;
}

// ----------------------------------------------- scatter edges into CSR(dst)
__global__ void k_scatter(const int* __restrict__ src, const int* __restrict__ dst,
                          const float* __restrict__ w, const float* __restrict__ dinv,
                          int* __restrict__ cursor,
                          int* __restrict__ srcs, float* __restrict__ coefs) {
    int e = blockIdx.x * 256 + threadIdx.x;
    if (e < N_EDGES) {
        int s = src[e], d = dst[e];
        int pos = atomicAdd(&cursor[d], 1);
        srcs[pos]  = s;
        coefs[pos] = dinv[s] * w[e] * dinv[d];
    }
}

// ------------------------------------------------------- fp32 GEMM  H = X @ W
// block: 256 threads, tile 64 rows x 128 cols, K=128 in two halves of 64.
// per thread: 8 rows x 4 cols = 32 accumulators.
__global__ __launch_bounds__(256)
void k_gemm(const float* __restrict__ X, const float* __restrict__ W,
            float* __restrict__ H) {
    __shared__ float Wl[64][128];   // 32 KB
    __shared__ float Xl[64][68];    // 17.4 KB (pad 64->68)
    int t = threadIdx.x;
    int rb = blockIdx.x * 64;
    int colb = (t & 31) * 4;        // output col base
    int rg = t >> 5;                // row group 0..7

    float acc[8][4] = {};

    for (int k0 = 0; k0 < 128; k0 += 64) {
        // stage W[k0..k0+63][0..127]: 8192 floats, 8 float4/thread, coalesced
        {
            const float4* Wg = (const float4*)(W + k0 * 128);
            float4* Ws = (float4*)&Wl[0][0];
#pragma unroll
            for (int j = 0; j < 8; ++j) Ws[t + 256 * j] = Wg[t + 256 * j];
        }
        // stage X[rb..rb+63][k0..k0+63]: 1024 float4, 4/thread
        {
#pragma unroll
            for (int j = 0; j < 4; ++j) {
                int idx = t + 256 * j;          // 0..1023
                int r = idx >> 4;               // 16 float4 per row
                int c4 = (idx & 15) * 4;
                int row = rb + r;
                float4 v = make_float4(0.f, 0.f, 0.f, 0.f);
                if (row < N_NODES) v = *(const float4*)(X + (size_t)row * FDIM + k0 + c4);
                *(float4*)&Xl[r][c4] = v;
            }
        }
        __syncthreads();
#pragma unroll
        for (int k = 0; k < 64; k += 4) {
            float4 wv0 = *(const float4*)&Wl[k + 0][colb];
            float4 wv1 = *(const float4*)&Wl[k + 1][colb];
            float4 wv2 = *(const float4*)&Wl[k + 2][colb];
            float4 wv3 = *(const float4*)&Wl[k + 3][colb];
#pragma unroll
            for (int r = 0; r < 8; ++r) {
                float4 xv = *(const float4*)&Xl[rg * 8 + r][k];
                acc[r][0] += xv.x * wv0.x; acc[r][1] += xv.x * wv0.y;
                acc[r][2] += xv.x * wv0.z; acc[r][3] += xv.x * wv0.w;
                acc[r][0] += xv.y * wv1.x; acc[r][1] += xv.y * wv1.y;
                acc[r][2] += xv.y * wv1.z; acc[r][3] += xv.y * wv1.w;
                acc[r][0] += xv.z * wv2.x; acc[r][1] += xv.z * wv2.y;
                acc[r][2] += xv.z * wv2.z; acc[r][3] += xv.z * wv2.w;
                acc[r][0] += xv.w * wv3.x; acc[r][1] += xv.w * wv3.y;
                acc[r][2] += xv.w * wv3.z; acc[r][3] += xv.w * wv3.w;
            }
        }
        __syncthreads();
    }
#pragma unroll
    for (int r = 0; r < 8; ++r) {
        int row = rb + rg * 8 + r;
        if (row < N_NODES)
            *(float4*)(H + (size_t)row * FDIM + colb) =
                make_float4(acc[r][0], acc[r][1], acc[r][2], acc[r][3]);
    }
}

// ------------------- aggregation + bias + L2-normalize + ReLU (1 wave / node)
__global__ __launch_bounds__(256)
void k_agg(const float* __restrict__ H, const int* __restrict__ rowptr,
           const int* __restrict__ srcs, const float* __restrict__ coefs,
           const float* __restrict__ dinv, const float* __restrict__ bias,
           float* __restrict__ out) {
    int wid  = threadIdx.x >> 6;
    int lane = threadIdx.x & 63;
    int node = blockIdx.x * 4 + wid;
    if (node >= N_NODES) return;

    float di = dinv[node];
    float2 acc;
    {   // self loop: coef = dinv[i]*1*dinv[i]
        float2 hv = *(const float2*)(H + (size_t)node * FDIM + lane * 2);
        float cs = di * di;
        acc.x = cs * hv.x; acc.y = cs * hv.y;
    }
    int e = rowptr[node], eend = rowptr[node + 1];
    for (; e + 4 <= eend; e += 4) {
        int   s0 = srcs[e],     s1 = srcs[e + 1], s2 = srcs[e + 2], s3 = srcs[e + 3];
        float c0 = coefs[e],    c1 = coefs[e + 1], c2 = coefs[e + 2], c3 = coefs[e + 3];
        float2 v0 = *(const float2*)(H + (size_t)s0 * FDIM + lane * 2);
        float2 v1 = *(const float2*)(H + (size_t)s1 * FDIM + lane * 2);
        float2 v2 = *(const float2*)(H + (size_t)s2 * FDIM + lane * 2);
        float2 v3 = *(const float2*)(H + (size_t)s3 * FDIM + lane * 2);
        acc.x += c0 * v0.x; acc.y += c0 * v0.y;
        acc.x += c1 * v1.x; acc.y += c1 * v1.y;
        acc.x += c2 * v2.x; acc.y += c2 * v2.y;
        acc.x += c3 * v3.x; acc.y += c3 * v3.y;
    }
    for (; e < eend; ++e) {
        int s = srcs[e]; float c = coefs[e];
        float2 v = *(const float2*)(H + (size_t)s * FDIM + lane * 2);
        acc.x += c * v.x; acc.y += c * v.y;
    }
    acc.x += bias[lane * 2];
    acc.y += bias[lane * 2 + 1];

    float ss = acc.x * acc.x + acc.y * acc.y;
#pragma unroll
    for (int off = 32; off >= 1; off >>= 1) ss += __shfl_xor(ss, off, 64);
    float n = sqrtf(ss);
    float inv = 1.0f / fmaxf(n, 1e-12f);
    float ox = fmaxf(acc.x * inv, 0.0f);
    float oy = fmaxf(acc.y * inv, 0.0f);
    *(float2*)(out + (size_t)node * FDIM + lane * 2) = make_float2(ox, oy);
}

// ------------------------------------- final linear: concat(o1,o2,o3) @ Wlin
__global__ __launch_bounds__(256)
void k_final(const float* __restrict__ o1, const float* __restrict__ o2,
             const float* __restrict__ o3, const float* __restrict__ Wlin,
             const float* __restrict__ blin, float* __restrict__ out) {
    __shared__ float Wt[C_OUT][384];   // transposed: Wt[c][f]
    __shared__ float bl[C_OUT];
    int t = threadIdx.x;
    for (int i = t; i < 384 * C_OUT; i += 256) {
        int f = i / C_OUT, c = i % C_OUT;
        Wt[c][f] = Wlin[i];
    }
    if (t < C_OUT) bl[t] = blin[t];
    __syncthreads();

    int wid = t >> 6, lane = t & 63;
    int node = blockIdx.x * 4 + wid;
    if (node >= N_NODES) return;

    size_t base = (size_t)node * FDIM;
    float v0 = o1[base + lane],       v1 = o1[base + 64 + lane];
    float v2 = o2[base + lane],       v3 = o2[base + 64 + lane];
    float v4 = o3[base + lane],       v5 = o3[base + 64 + lane];

    float acc[C_OUT];
#pragma unroll
    for (int c = 0; c < C_OUT; ++c) {
        acc[c] = v0 * Wt[c][lane]       + v1 * Wt[c][64 + lane]
               + v2 * Wt[c][128 + lane] + v3 * Wt[c][192 + lane]
               + v4 * Wt[c][256 + lane] + v5 * Wt[c][320 + lane];
    }
#pragma unroll
    for (int c = 0; c < C_OUT; ++c)
#pragma unroll
        for (int off = 32; off >= 1; off >>= 1) acc[c] += __shfl_xor(acc[c], off, 64);
    if (lane == 0) {
#pragma unroll
        for (int c = 0; c < C_OUT; ++c)
            out[(size_t)node * C_OUT + c] = acc[c] + bl[c];
    }
}

// -------------------------------------------------------------------- launch
extern "C" void kernel_launch(void* const* d_in, const int* in_sizes, int n_in,
                              void* d_out, int out_size, void* d_ws, size_t ws_size,
                              hipStream_t stream) {
    const float* x  = (const float*)d_in[0];
    const int*   ei = (const int*)d_in[1];
    const float* ew = (const float*)d_in[2];
    const float* W1 = (const float*)d_in[3];
    const float* b1 = (const float*)d_in[4];
    const float* W2 = (const float*)d_in[5];
    const float* b2 = (const float*)d_in[6];
    const float* W3 = (const float*)d_in[7];
    const float* b3 = (const float*)d_in[8];
    const float* Wl = (const float*)d_in[9];
    const float* bl = (const float*)d_in[10];
    float* out = (float*)d_out;

    const int* srcI = ei;             // edge_index[0]
    const int* dstI = ei + N_EDGES;   // edge_index[1]

    char* p = (char*)d_ws;
    auto alloc = [&](size_t bytes) {
        char* r = p;
        p += (bytes + 255) & ~(size_t)255;
        return r;
    };
    float* deg    = (float*)alloc((size_t)N_NODES * 4);
    float* dinv   = (float*)alloc((size_t)N_NODES * 4);
    int*   cursor = (int*)  alloc((size_t)N_NODES * 4);       // counts -> cursor
    int*   rowptr = (int*)  alloc((size_t)(N_NODES + 1) * 4);
    int*   srcs   = (int*)  alloc((size_t)N_EDGES * 4);
    float* coefs  = (float*)alloc((size_t)N_EDGES * 4);
    float* h      = (float*)alloc((size_t)N_NODES * FDIM * 4);
    float* o1     = (float*)alloc((size_t)N_NODES * FDIM * 4);
    float* o2     = (float*)alloc((size_t)N_NODES * FDIM * 4);
    float* o3     = (float*)alloc((size_t)N_NODES * FDIM * 4);

    k_init   <<<(N_NODES + 255) / 256, 256, 0, stream>>>(deg, cursor);
    k_deg_hist<<<(N_EDGES + 255) / 256, 256, 0, stream>>>(srcI, dstI, ew, deg, cursor);
    k_scan   <<<1, 1024, 0, stream>>>(deg, dinv, cursor, rowptr);
    k_scatter<<<(N_EDGES + 255) / 256, 256, 0, stream>>>(srcI, dstI, ew, dinv, cursor, srcs, coefs);

    const float* Wmats[3] = {W1, W2, W3};
    const float* bvecs[3] = {b1, b2, b3};
    float* outs[3] = {o1, o2, o3};
    const float* in = x;
    for (int l = 0; l < 3; ++l) {
        k_gemm<<<(N_NODES + 63) / 64, 256, 0, stream>>>(in, Wmats[l], h);
        k_agg <<<N_NODES / 4, 256, 0, stream>>>(h, rowptr, srcs, coefs, dinv, bvecs[l], outs[l]);
        in = outs[l];
    }
    k_final<<<N_NODES / 4, 256, 0, stream>>>(o1, o2, o3, Wl, bl, out);
}

// Round 3
// 805.409 us; speedup vs baseline: 1.2589x; 1.2589x over previous
//
#include <hip/hip_runtime.h>

#define N_NODES 50000
#define N_EDGES 1600000
#define FDIM    128
#define C_OUT   10
#define NBLK    ((N_NODES + 255) / 256)   // 196

// ---------------------------------------------------------------- init
__global__ void k_init(float* __restrict__ deg, int* __restrict__ cnt) {
    int i = blockIdx.x * 256 + threadIdx.x;
    if (i < N_NODES) { deg[i] = 1.0f; cnt[i] = 0; }   // self-loop weight 1 pre-added
}

// ------------------------------------------------- degree + dst histogram
__global__ void k_deg_hist(const int* __restrict__ src, const int* __restrict__ dst,
                           const float* __restrict__ w,
                           float* __restrict__ deg, int* __restrict__ cnt) {
    int e = blockIdx.x * 256 + threadIdx.x;
    if (e < N_EDGES) {
        int d = dst[e];
        atomicAdd(&deg[d], w[e]);
        atomicAdd(&cnt[d], 1);
    }
}

// ---------------------------------------------------- multi-block scan (1/3)
// per-block sum of 256 counts
__global__ __launch_bounds__(256)
void k_scan1(const int* __restrict__ cnt, int* __restrict__ blocksum) {
    int i = blockIdx.x * 256 + threadIdx.x;
    int v = (i < N_NODES) ? cnt[i] : 0;
#pragma unroll
    for (int off = 32; off >= 1; off >>= 1) v += __shfl_xor(v, off, 64);
    __shared__ int ws[4];
    if ((threadIdx.x & 63) == 0) ws[threadIdx.x >> 6] = v;
    __syncthreads();
    if (threadIdx.x == 0) blocksum[blockIdx.x] = ws[0] + ws[1] + ws[2] + ws[3];
}

// ---------------------------------------------------- multi-block scan (2/3)
// exclusive scan of NBLK block sums (single small block)
__global__ __launch_bounds__(256)
void k_scan2(int* __restrict__ blocksum) {
    int t = threadIdx.x, lane = t & 63, w = t >> 6;
    int v = (t < NBLK) ? blocksum[t] : 0;
    int x = v;
#pragma unroll
    for (int off = 1; off < 64; off <<= 1) {
        int y = __shfl_up(x, off, 64);
        if (lane >= off) x += y;
    }
    __shared__ int ws[4];
    if (lane == 63) ws[w] = x;
    __syncthreads();
    int add = 0;
    for (int j = 0; j < w; ++j) add += ws[j];
    if (t < NBLK) blocksum[t] = add + x - v;   // exclusive
}

// ---------------------------------------------------- multi-block scan (3/3)
// intra-block exclusive scan + block offset -> rowptr/cursor; also dinv
__global__ __launch_bounds__(256)
void k_scan3(int* __restrict__ cnt_cursor, const int* __restrict__ blocksum,
             const float* __restrict__ deg, float* __restrict__ dinv,
             int* __restrict__ rowptr) {
    int i = blockIdx.x * 256 + threadIdx.x;
    int t = threadIdx.x, lane = t & 63, w = t >> 6;
    int v = (i < N_NODES) ? cnt_cursor[i] : 0;
    int x = v;
#pragma unroll
    for (int off = 1; off < 64; off <<= 1) {
        int y = __shfl_up(x, off, 64);
        if (lane >= off) x += y;
    }
    __shared__ int ws[4];
    if (lane == 63) ws[w] = x;
    __syncthreads();
    int add = blocksum[blockIdx.x];
    for (int j = 0; j < w; ++j) add += ws[j];
    int excl = add + x - v;
    if (i < N_NODES) {
        rowptr[i] = excl;
        cnt_cursor[i] = excl;                  // becomes scatter cursor
        float dg = deg[i];
        dinv[i] = dg > 0.0f ? rsqrtf(dg) : 0.0f;
        if (i == N_NODES - 1) rowptr[N_NODES] = N_EDGES;
    }
}

// ----------------------------------------------- scatter edges into CSR(dst)
// packed (src, coef) as int2 -> one 8B scattered store
__global__ void k_scatter(const int* __restrict__ src, const int* __restrict__ dst,
                          const float* __restrict__ w, const float* __restrict__ dinv,
                          int* __restrict__ cursor, int2* __restrict__ edat) {
    int e = blockIdx.x * 256 + threadIdx.x;
    if (e < N_EDGES) {
        int s = src[e], d = dst[e];
        int pos = atomicAdd(&cursor[d], 1);
        float c = dinv[s] * w[e] * dinv[d];
        edat[pos] = make_int2(s, __float_as_int(c));
    }
}

// ------------------------------------------------------- fp32 GEMM  H = X @ W
__global__ __launch_bounds__(256)
void k_gemm(const float* __restrict__ X, const float* __restrict__ W,
            float* __restrict__ H) {
    __shared__ float Wl[64][128];   // 32 KB
    __shared__ float Xl[64][68];    // 17.4 KB (pad 64->68)
    int t = threadIdx.x;
    int rb = blockIdx.x * 64;
    int colb = (t & 31) * 4;        // output col base
    int rg = t >> 5;                // row group 0..7

    float acc[8][4] = {};

    for (int k0 = 0; k0 < 128; k0 += 64) {
        {
            const float4* Wg = (const float4*)(W + k0 * 128);
            float4* Ws = (float4*)&Wl[0][0];
#pragma unroll
            for (int j = 0; j < 8; ++j) Ws[t + 256 * j] = Wg[t + 256 * j];
        }
        {
#pragma unroll
            for (int j = 0; j < 4; ++j) {
                int idx = t + 256 * j;          // 0..1023
                int r = idx >> 4;               // 16 float4 per row
                int c4 = (idx & 15) * 4;
                int row = rb + r;
                float4 v = make_float4(0.f, 0.f, 0.f, 0.f);
                if (row < N_NODES) v = *(const float4*)(X + (size_t)row * FDIM + k0 + c4);
                *(float4*)&Xl[r][c4] = v;
            }
        }
        __syncthreads();
#pragma unroll
        for (int k = 0; k < 64; k += 4) {
            float4 wv0 = *(const float4*)&Wl[k + 0][colb];
            float4 wv1 = *(const float4*)&Wl[k + 1][colb];
            float4 wv2 = *(const float4*)&Wl[k + 2][colb];
            float4 wv3 = *(const float4*)&Wl[k + 3][colb];
#pragma unroll
            for (int r = 0; r < 8; ++r) {
                float4 xv = *(const float4*)&Xl[rg * 8 + r][k];
                acc[r][0] += xv.x * wv0.x; acc[r][1] += xv.x * wv0.y;
                acc[r][2] += xv.x * wv0.z; acc[r][3] += xv.x * wv0.w;
                acc[r][0] += xv.y * wv1.x; acc[r][1] += xv.y * wv1.y;
                acc[r][2] += xv.y * wv1.z; acc[r][3] += xv.y * wv1.w;
                acc[r][0] += xv.z * wv2.x; acc[r][1] += xv.z * wv2.y;
                acc[r][2] += xv.z * wv2.z; acc[r][3] += xv.z * wv2.w;
                acc[r][0] += xv.w * wv3.x; acc[r][1] += xv.w * wv3.y;
                acc[r][2] += xv.w * wv3.z; acc[r][3] += xv.w * wv3.w;
            }
        }
        __syncthreads();
    }
#pragma unroll
    for (int r = 0; r < 8; ++r) {
        int row = rb + rg * 8 + r;
        if (row < N_NODES)
            *(float4*)(H + (size_t)row * FDIM + colb) =
                make_float4(acc[r][0], acc[r][1], acc[r][2], acc[r][3]);
    }
}

// ------------------- aggregation + bias + L2-normalize + ReLU (1 wave / node)
__global__ __launch_bounds__(256)
void k_agg(const float* __restrict__ H, const int* __restrict__ rowptr,
           const int2* __restrict__ edat, const float* __restrict__ dinv,
           const float* __restrict__ bias, float* __restrict__ out) {
    int wid  = threadIdx.x >> 6;
    int lane = threadIdx.x & 63;
    int node = blockIdx.x * 4 + wid;
    if (node >= N_NODES) return;

    float di = dinv[node];
    float2 acc;
    {   // self loop: coef = dinv[i]*1*dinv[i]
        float2 hv = *(const float2*)(H + (size_t)node * FDIM + lane * 2);
        float cs = di * di;
        acc.x = cs * hv.x; acc.y = cs * hv.y;
    }
    int e = rowptr[node], eend = rowptr[node + 1];
    for (; e + 4 <= eend; e += 4) {
        int2 e0 = edat[e], e1 = edat[e + 1], e2 = edat[e + 2], e3 = edat[e + 3];
        float2 v0 = *(const float2*)(H + (size_t)e0.x * FDIM + lane * 2);
        float2 v1 = *(const float2*)(H + (size_t)e1.x * FDIM + lane * 2);
        float2 v2 = *(const float2*)(H + (size_t)e2.x * FDIM + lane * 2);
        float2 v3 = *(const float2*)(H + (size_t)e3.x * FDIM + lane * 2);
        float c0 = __int_as_float(e0.y), c1 = __int_as_float(e1.y);
        float c2 = __int_as_float(e2.y), c3 = __int_as_float(e3.y);
        acc.x += c0 * v0.x; acc.y += c0 * v0.y;
        acc.x += c1 * v1.x; acc.y += c1 * v1.y;
        acc.x += c2 * v2.x; acc.y += c2 * v2.y;
        acc.x += c3 * v3.x; acc.y += c3 * v3.y;
    }
    for (; e < eend; ++e) {
        int2 ed = edat[e];
        float c = __int_as_float(ed.y);
        float2 v = *(const float2*)(H + (size_t)ed.x * FDIM + lane * 2);
        acc.x += c * v.x; acc.y += c * v.y;
    }
    acc.x += bias[lane * 2];
    acc.y += bias[lane * 2 + 1];

    float ss = acc.x * acc.x + acc.y * acc.y;
#pragma unroll
    for (int off = 32; off >= 1; off >>= 1) ss += __shfl_xor(ss, off, 64);
    float n = sqrtf(ss);
    float inv = 1.0f / fmaxf(n, 1e-12f);
    float ox = fmaxf(acc.x * inv, 0.0f);
    float oy = fmaxf(acc.y * inv, 0.0f);
    *(float2*)(out + (size_t)node * FDIM + lane * 2) = make_float2(ox, oy);
}

// ------------------------------------- final linear: concat(o1,o2,o3) @ Wlin
__global__ __launch_bounds__(256)
void k_final(const float* __restrict__ o1, const float* __restrict__ o2,
             const float* __restrict__ o3, const float* __restrict__ Wlin,
             const float* __restrict__ blin, float* __restrict__ out) {
    __shared__ float Wt[C_OUT][384];   // transposed: Wt[c][f]
    __shared__ float bl[C_OUT];
    int t = threadIdx.x;
    for (int i = t; i < 384 * C_OUT; i += 256) {
        int f = i / C_OUT, c = i % C_OUT;
        Wt[c][f] = Wlin[i];
    }
    if (t < C_OUT) bl[t] = blin[t];
    __syncthreads();

    int wid = t >> 6, lane = t & 63;
    int node = blockIdx.x * 4 + wid;
    if (node >= N_NODES) return;

    size_t base = (size_t)node * FDIM;
    float v0 = o1[base + lane],       v1 = o1[base + 64 + lane];
    float v2 = o2[base + lane],       v3 = o2[base + 64 + lane];
    float v4 = o3[base + lane],       v5 = o3[base + 64 + lane];

    float acc[C_OUT];
#pragma unroll
    for (int c = 0; c < C_OUT; ++c) {
        acc[c] = v0 * Wt[c][lane]       + v1 * Wt[c][64 + lane]
               + v2 * Wt[c][128 + lane] + v3 * Wt[c][192 + lane]
               + v4 * Wt[c][256 + lane] + v5 * Wt[c][320 + lane];
    }
#pragma unroll
    for (int c = 0; c < C_OUT; ++c)
#pragma unroll
        for (int off = 32; off >= 1; off >>= 1) acc[c] += __shfl_xor(acc[c], off, 64);
    if (lane == 0) {
#pragma unroll
        for (int c = 0; c < C_OUT; ++c)
            out[(size_t)node * C_OUT + c] = acc[c] + bl[c];
    }
}

// -------------------------------------------------------------------- launch
extern "C" void kernel_launch(void* const* d_in, const int* in_sizes, int n_in,
                              void* d_out, int out_size, void* d_ws, size_t ws_size,
                              hipStream_t stream) {
    const float* x  = (const float*)d_in[0];
    const int*   ei = (const int*)d_in[1];
    const float* ew = (const float*)d_in[2];
    const float* W1 = (const float*)d_in[3];
    const float* b1 = (const float*)d_in[4];
    const float* W2 = (const float*)d_in[5];
    const float* b2 = (const float*)d_in[6];
    const float* W3 = (const float*)d_in[7];
    const float* b3 = (const float*)d_in[8];
    const float* Wl = (const float*)d_in[9];
    const float* bl = (const float*)d_in[10];
    float* out = (float*)d_out;

    const int* srcI = ei;             // edge_index[0]
    const int* dstI = ei + N_EDGES;   // edge_index[1]

    char* p = (char*)d_ws;
    auto alloc = [&](size_t bytes) {
        char* r = p;
        p += (bytes + 255) & ~(size_t)255;
        return r;
    };
    float* deg    = (float*)alloc((size_t)N_NODES * 4);
    float* dinv   = (float*)alloc((size_t)N_NODES * 4);
    int*   cursor = (int*)  alloc((size_t)N_NODES * 4);       // counts -> cursor
    int*   rowptr = (int*)  alloc((size_t)(N_NODES + 1) * 4);
    int*   bsum   = (int*)  alloc((size_t)NBLK * 4);
    int2*  edat   = (int2*) alloc((size_t)N_EDGES * 8);
    float* h      = (float*)alloc((size_t)N_NODES * FDIM * 4);
    float* o1     = (float*)alloc((size_t)N_NODES * FDIM * 4);
    float* o2     = (float*)alloc((size_t)N_NODES * FDIM * 4);
    float* o3     = (float*)alloc((size_t)N_NODES * FDIM * 4);

    k_init    <<<NBLK, 256, 0, stream>>>(deg, cursor);
    k_deg_hist<<<(N_EDGES + 255) / 256, 256, 0, stream>>>(srcI, dstI, ew, deg, cursor);
    k_scan1   <<<NBLK, 256, 0, stream>>>(cursor, bsum);
    k_scan2   <<<1, 256, 0, stream>>>(bsum);
    k_scan3   <<<NBLK, 256, 0, stream>>>(cursor, bsum, deg, dinv, rowptr);
    k_scatter <<<(N_EDGES + 255) / 256, 256, 0, stream>>>(srcI, dstI, ew, dinv, cursor, edat);

    const float* Wmats[3] = {W1, W2, W3};
    const float* bvecs[3] = {b1, b2, b3};
    float* outs[3] = {o1, o2, o3};
    const float* in = x;
    for (int l = 0; l < 3; ++l) {
        k_gemm<<<(N_NODES + 63) / 64, 256, 0, stream>>>(in, Wmats[l], h);
        k_agg <<<N_NODES / 4, 256, 0, stream>>>(h, rowptr, edat, dinv, bvecs[l], outs[l]);
        in = outs[l];
    }
    k_final<<<N_NODES / 4, 256, 0, stream>>>(o1, o2, o3, Wl, bl, out);
}

// Round 5
// 746.095 us; speedup vs baseline: 1.3590x; 1.0795x over previous
//
#include <hip/hip_runtime.h>

#define N_NODES 50000
#define N_EDGES 1600000
#define FDIM    128
#define C_OUT   10
#define NBLK    ((N_NODES + 255) / 256)   // 196

typedef unsigned long long u64;
#define FX_BITS 44
#define FX_MASK ((1ull << FX_BITS) - 1)
#define FX_SCALE 4294967296.0   // 2^32

// ---------------------------------------------------------------- init
__global__ void k_init(u64* __restrict__ hist) {
    int i = blockIdx.x * 256 + threadIdx.x;
    if (i < N_NODES) hist[i] = 0ull;
}

// ----------------- degree + dst histogram: ONE packed 64-bit atomic per edge
// bits [63:44] = count, bits [43:0] = sum(w) in 2^32 fixed point
__global__ void k_hist(const int* __restrict__ dst, const float* __restrict__ w,
                       u64* __restrict__ hist) {
    int e = blockIdx.x * 256 + threadIdx.x;
    if (e < N_EDGES) {
        u64 fx = (u64)((double)w[e] * FX_SCALE + 0.5);
        u64 packed = (1ull << FX_BITS) | fx;
        atomicAdd(&hist[dst[e]], packed);
    }
}

// ---------------------------------------------------- multi-block scan (1/3)
__global__ __launch_bounds__(256)
void k_scan1(const u64* __restrict__ hist, int* __restrict__ blocksum) {
    int i = blockIdx.x * 256 + threadIdx.x;
    int v = (i < N_NODES) ? (int)(hist[i] >> FX_BITS) : 0;
#pragma unroll
    for (int off = 32; off >= 1; off >>= 1) v += __shfl_xor(v, off, 64);
    __shared__ int ws[4];
    if ((threadIdx.x & 63) == 0) ws[threadIdx.x >> 6] = v;
    __syncthreads();
    if (threadIdx.x == 0) blocksum[blockIdx.x] = ws[0] + ws[1] + ws[2] + ws[3];
}

// ---------------------------------------------------- multi-block scan (2/3)
__global__ __launch_bounds__(256)
void k_scan2(int* __restrict__ blocksum) {
    int t = threadIdx.x, lane = t & 63, w = t >> 6;
    int v = (t < NBLK) ? blocksum[t] : 0;
    int x = v;
#pragma unroll
    for (int off = 1; off < 64; off <<= 1) {
        int y = __shfl_up(x, off, 64);
        if (lane >= off) x += y;
    }
    __shared__ int ws[4];
    if (lane == 63) ws[w] = x;
    __syncthreads();
    int add = 0;
    for (int j = 0; j < w; ++j) add += ws[j];
    if (t < NBLK) blocksum[t] = add + x - v;   // exclusive
}

// ------------------------- multi-block scan (3/3): rowptr + cursor + dinv
__global__ __launch_bounds__(256)
void k_scan3(const u64* __restrict__ hist, const int* __restrict__ blocksum,
             float* __restrict__ dinv, int* __restrict__ cursor,
             int* __restrict__ rowptr) {
    int i = blockIdx.x * 256 + threadIdx.x;
    int t = threadIdx.x, lane = t & 63, w = t >> 6;
    u64 hv = (i < N_NODES) ? hist[i] : 0ull;
    int v = (int)(hv >> FX_BITS);
    int x = v;
#pragma unroll
    for (int off = 1; off < 64; off <<= 1) {
        int y = __shfl_up(x, off, 64);
        if (lane >= off) x += y;
    }
    __shared__ int ws[4];
    if (lane == 63) ws[w] = x;
    __syncthreads();
    int add = blocksum[blockIdx.x];
    for (int j = 0; j < w; ++j) add += ws[j];
    int excl = add + x - v;
    if (i < N_NODES) {
        rowptr[i] = excl;
        cursor[i] = excl;
        // deg = 1 (self-loop) + fixed-point weight sum
        float dg = 1.0f + (float)((double)(hv & FX_MASK) * (1.0 / FX_SCALE));
        dinv[i] = rsqrtf(dg);                  // dg >= 1 always
        if (i == N_NODES - 1) rowptr[N_NODES] = N_EDGES;
    }
}

// ----------------------------------------------- scatter edges into CSR(dst)
__global__ void k_scatter(const int* __restrict__ src, const int* __restrict__ dst,
                          const float* __restrict__ w, const float* __restrict__ dinv,
                          int* __restrict__ cursor, int2* __restrict__ edat) {
    int e = blockIdx.x * 256 + threadIdx.x;
    if (e < N_EDGES) {
        int s = src[e], d = dst[e];
        int pos = atomicAdd(&cursor[d], 1);
        float c = dinv[s] * w[e] * dinv[d];
        edat[pos] = make_int2(s, __float_as_int(c));
    }
}

// ------------------------------------------------------- fp32 GEMM  H = X @ W
__global__ __launch_bounds__(256)
void k_gemm(const float* __restrict__ X, const float* __restrict__ W,
            float* __restrict__ H) {
    __shared__ float Wl[64][128];   // 32 KB
    __shared__ float Xl[64][68];    // 17.4 KB (pad 64->68)
    int t = threadIdx.x;
    int rb = blockIdx.x * 64;
    int colb = (t & 31) * 4;        // output col base
    int rg = t >> 5;                // row group 0..7

    float acc[8][4] = {};

    for (int k0 = 0; k0 < 128; k0 += 64) {
        {
            const float4* Wg = (const float4*)(W + k0 * 128);
            float4* Ws = (float4*)&Wl[0][0];
#pragma unroll
            for (int j = 0; j < 8; ++j) Ws[t + 256 * j] = Wg[t + 256 * j];
        }
        {
#pragma unroll
            for (int j = 0; j < 4; ++j) {
                int idx = t + 256 * j;          // 0..1023
                int r = idx >> 4;               // 16 float4 per row
                int c4 = (idx & 15) * 4;
                int row = rb + r;
                float4 v = make_float4(0.f, 0.f, 0.f, 0.f);
                if (row < N_NODES) v = *(const float4*)(X + (size_t)row * FDIM + k0 + c4);
                *(float4*)&Xl[r][c4] = v;
            }
        }
        __syncthreads();
#pragma unroll
        for (int k = 0; k < 64; k += 4) {
            float4 wv0 = *(const float4*)&Wl[k + 0][colb];
            float4 wv1 = *(const float4*)&Wl[k + 1][colb];
            float4 wv2 = *(const float4*)&Wl[k + 2][colb];
            float4 wv3 = *(const float4*)&Wl[k + 3][colb];
#pragma unroll
            for (int r = 0; r < 8; ++r) {
                float4 xv = *(const float4*)&Xl[rg * 8 + r][k];
                acc[r][0] += xv.x * wv0.x; acc[r][1] += xv.x * wv0.y;
                acc[r][2] += xv.x * wv0.z; acc[r][3] += xv.x * wv0.w;
                acc[r][0] += xv.y * wv1.x; acc[r][1] += xv.y * wv1.y;
                acc[r][2] += xv.y * wv1.z; acc[r][3] += xv.y * wv1.w;
                acc[r][0] += xv.z * wv2.x; acc[r][1] += xv.z * wv2.y;
                acc[r][2] += xv.z * wv2.z; acc[r][3] += xv.z * wv2.w;
                acc[r][0] += xv.w * wv3.x; acc[r][1] += xv.w * wv3.y;
                acc[r][2] += xv.w * wv3.z; acc[r][3] += xv.w * wv3.w;
            }
        }
        __syncthreads();
    }
#pragma unroll
    for (int r = 0; r < 8; ++r) {
        int row = rb + rg * 8 + r;
        if (row < N_NODES)
            *(float4*)(H + (size_t)row * FDIM + colb) =
                make_float4(acc[r][0], acc[r][1], acc[r][2], acc[r][3]);
    }
}

// ------------------- aggregation + bias + L2-normalize + ReLU (1 wave / node)
__global__ __launch_bounds__(256)
void k_agg(const float* __restrict__ H, const int* __restrict__ rowptr,
           const int2* __restrict__ edat, const float* __restrict__ dinv,
           const float* __restrict__ bias, float* __restrict__ out) {
    int wid  = threadIdx.x >> 6;
    int lane = threadIdx.x & 63;
    int node = blockIdx.x * 4 + wid;
    if (node >= N_NODES) return;

    float di = dinv[node];
    float2 acc;
    {   // self loop: coef = dinv[i]*1*dinv[i]
        float2 hv = *(const float2*)(H + (size_t)node * FDIM + lane * 2);
        float cs = di * di;
        acc.x = cs * hv.x; acc.y = cs * hv.y;
    }
    int e = rowptr[node], eend = rowptr[node + 1];
    for (; e + 4 <= eend; e += 4) {
        int2 e0 = edat[e], e1 = edat[e + 1], e2 = edat[e + 2], e3 = edat[e + 3];
        float2 v0 = *(const float2*)(H + (size_t)e0.x * FDIM + lane * 2);
        float2 v1 = *(const float2*)(H + (size_t)e1.x * FDIM + lane * 2);
        float2 v2 = *(const float2*)(H + (size_t)e2.x * FDIM + lane * 2);
        float2 v3 = *(const float2*)(H + (size_t)e3.x * FDIM + lane * 2);
        float c0 = __int_as_float(e0.y), c1 = __int_as_float(e1.y);
        float c2 = __int_as_float(e2.y), c3 = __int_as_float(e3.y);
        acc.x += c0 * v0.x; acc.y += c0 * v0.y;
        acc.x += c1 * v1.x; acc.y += c1 * v1.y;
        acc.x += c2 * v2.x; acc.y += c2 * v2.y;
        acc.x += c3 * v3.x; acc.y += c3 * v3.y;
    }
    for (; e < eend; ++e) {
        int2 ed = edat[e];
        float c = __int_as_float(ed.y);
        float2 v = *(const float2*)(H + (size_t)ed.x * FDIM + lane * 2);
        acc.x += c * v.x; acc.y += c * v.y;
    }
    acc.x += bias[lane * 2];
    acc.y += bias[lane * 2 + 1];

    float ss = acc.x * acc.x + acc.y * acc.y;
#pragma unroll
    for (int off = 32; off >= 1; off >>= 1) ss += __shfl_xor(ss, off, 64);
    float n = sqrtf(ss);
    float inv = 1.0f / fmaxf(n, 1e-12f);
    float ox = fmaxf(acc.x * inv, 0.0f);
    float oy = fmaxf(acc.y * inv, 0.0f);
    *(float2*)(out + (size_t)node * FDIM + lane * 2) = make_float2(ox, oy);
}

// ------------------------------------- final linear: concat(o1,o2,o3) @ Wlin
__global__ __launch_bounds__(256)
void k_final(const float* __restrict__ o1, const float* __restrict__ o2,
             const float* __restrict__ o3, const float* __restrict__ Wlin,
             const float* __restrict__ blin, float* __restrict__ out) {
    __shared__ float Wt[C_OUT][384];   // transposed: Wt[c][f]
    __shared__ float bl[C_OUT];
    int t = threadIdx.x;
    for (int i = t; i < 384 * C_OUT; i += 256) {
        int f = i / C_OUT, c = i % C_OUT;
        Wt[c][f] = Wlin[i];
    }
    if (t < C_OUT) bl[t] = blin[t];
    __syncthreads();

    int wid = t >> 6, lane = t & 63;
    int node = blockIdx.x * 4 + wid;
    if (node >= N_NODES) return;

    size_t base = (size_t)node * FDIM;
    float v0 = o1[base + lane],       v1 = o1[base + 64 + lane];
    float v2 = o2[base + lane],       v3 = o2[base + 64 + lane];
    float v4 = o3[base + lane],       v5 = o3[base + 64 + lane];

    float acc[C_OUT];
#pragma unroll
    for (int c = 0; c < C_OUT; ++c) {
        acc[c] = v0 * Wt[c][lane]       + v1 * Wt[c][64 + lane]
               + v2 * Wt[c][128 + lane] + v3 * Wt[c][192 + lane]
               + v4 * Wt[c][256 + lane] + v5 * Wt[c][320 + lane];
    }
#pragma unroll
    for (int c = 0; c < C_OUT; ++c)
#pragma unroll
        for (int off = 32; off >= 1; off >>= 1) acc[c] += __shfl_xor(acc[c], off, 64);
    if (lane == 0) {
#pragma unroll
        for (int c = 0; c < C_OUT; ++c)
            out[(size_t)node * C_OUT + c] = acc[c] + bl[c];
    }
}

// -------------------------------------------------------------------- launch
extern "C" void kernel_launch(void* const* d_in, const int* in_sizes, int n_in,
                              void* d_out, int out_size, void* d_ws, size_t ws_size,
                              hipStream_t stream) {
    const float* x  = (const float*)d_in[0];
    const int*   ei = (const int*)d_in[1];
    const float* ew = (const float*)d_in[2];
    const float* W1 = (const float*)d_in[3];
    const float* b1 = (const float*)d_in[4];
    const float* W2 = (const float*)d_in[5];
    const float* b2 = (const float*)d_in[6];
    const float* W3 = (const float*)d_in[7];
    const float* b3 = (const float*)d_in[8];
    const float* Wl = (const float*)d_in[9];
    const float* bl = (const float*)d_in[10];
    float* out = (float*)d_out;

    const int* srcI = ei;             // edge_index[0]
    const int* dstI = ei + N_EDGES;   // edge_index[1]

    char* p = (char*)d_ws;
    auto alloc = [&](size_t bytes) {
        char* r = p;
        p += (bytes + 255) & ~(size_t)255;
        return r;
    };
    u64*   hist   = (u64*)  alloc((size_t)N_NODES * 8);
    float* dinv   = (float*)alloc((size_t)N_NODES * 4);
    int*   cursor = (int*)  alloc((size_t)N_NODES * 4);
    int*   rowptr = (int*)  alloc((size_t)(N_NODES + 1) * 4);
    int*   bsum   = (int*)  alloc((size_t)NBLK * 4);
    int2*  edat   = (int2*) alloc((size_t)N_EDGES * 8);
    float* h      = (float*)alloc((size_t)N_NODES * FDIM * 4);
    float* o1     = (float*)alloc((size_t)N_NODES * FDIM * 4);
    float* o2     = (float*)alloc((size_t)N_NODES * FDIM * 4);
    float* o3     = (float*)alloc((size_t)N_NODES * FDIM * 4);

    k_init   <<<NBLK, 256, 0, stream>>>(hist);
    k_hist   <<<(N_EDGES + 255) / 256, 256, 0, stream>>>(dstI, ew, hist);
    k_scan1  <<<NBLK, 256, 0, stream>>>(hist, bsum);
    k_scan2  <<<1, 256, 0, stream>>>(bsum);
    k_scan3  <<<NBLK, 256, 0, stream>>>(hist, bsum, dinv, cursor, rowptr);
    k_scatter<<<(N_EDGES + 255) / 256, 256, 0, stream>>>(srcI, dstI, ew, dinv, cursor, edat);

    const float* Wmats[3] = {W1, W2, W3};
    const float* bvecs[3] = {b1, b2, b3};
    float* outs[3] = {o1, o2, o3};
    const float* in = x;
    for (int l = 0; l < 3; ++l) {
        k_gemm<<<(N_NODES + 63) / 64, 256, 0, stream>>>(in, Wmats[l], h);
        k_agg <<<N_NODES / 4, 256, 0, stream>>>(h, rowptr, edat, dinv, bvecs[l], outs[l]);
        in = outs[l];
    }
    k_final<<<N_NODES / 4, 256, 0, stream>>>(o1, o2, o3, Wl, bl, out);
}

// Round 6
// 605.051 us; speedup vs baseline: 1.6758x; 1.2331x over previous
//
#include <hip/hip_runtime.h>
#include <hip/hip_fp16.h>

#define N_NODES 50000
#define N_EDGES 1600000
#define FDIM    128
#define C_OUT   10
#define NBLK    ((N_NODES + 255) / 256)   // 196

typedef unsigned long long u64;
typedef unsigned int u32;
typedef unsigned short u16;
#define FX_BITS 44
#define FX_MASK ((1ull << FX_BITS) - 1)
#define FX_SCALE 4294967296.0   // 2^32

__device__ __forceinline__ u32 pack_h2(float a, float b) {
    __half2 h = __floats2half2_rn(a, b);
    return *(u32*)&h;
}
__device__ __forceinline__ float2 unpack_h2(u32 u) {
    __half2 h = *(__half2*)&u;
    return __half22float2(h);
}

// ---------------------------------------------------------------- init
__global__ void k_init(u64* __restrict__ hist) {
    int i = blockIdx.x * 256 + threadIdx.x;
    if (i < N_NODES) hist[i] = 0ull;
}

// ----------------- degree + dst histogram: ONE packed 64-bit atomic per edge
// bits [63:44] = count, bits [43:0] = sum(w) in 2^32 fixed point
__global__ void k_hist(const int* __restrict__ dst, const float* __restrict__ w,
                       u64* __restrict__ hist) {
    int e = blockIdx.x * 256 + threadIdx.x;
    if (e < N_EDGES) {
        u64 fx = (u64)((double)w[e] * FX_SCALE + 0.5);
        u64 packed = (1ull << FX_BITS) | fx;
        atomicAdd(&hist[dst[e]], packed);
    }
}

// ---------------------------------------------------- multi-block scan (1/3)
__global__ __launch_bounds__(256)
void k_scan1(const u64* __restrict__ hist, int* __restrict__ blocksum) {
    int i = blockIdx.x * 256 + threadIdx.x;
    int v = (i < N_NODES) ? (int)(hist[i] >> FX_BITS) : 0;
#pragma unroll
    for (int off = 32; off >= 1; off >>= 1) v += __shfl_xor(v, off, 64);
    __shared__ int ws[4];
    if ((threadIdx.x & 63) == 0) ws[threadIdx.x >> 6] = v;
    __syncthreads();
    if (threadIdx.x == 0) blocksum[blockIdx.x] = ws[0] + ws[1] + ws[2] + ws[3];
}

// ---------------------------------------------------- multi-block scan (2/3)
__global__ __launch_bounds__(256)
void k_scan2(int* __restrict__ blocksum) {
    int t = threadIdx.x, lane = t & 63, w = t >> 6;
    int v = (t < NBLK) ? blocksum[t] : 0;
    int x = v;
#pragma unroll
    for (int off = 1; off < 64; off <<= 1) {
        int y = __shfl_up(x, off, 64);
        if (lane >= off) x += y;
    }
    __shared__ int ws[4];
    if (lane == 63) ws[w] = x;
    __syncthreads();
    int add = 0;
    for (int j = 0; j < w; ++j) add += ws[j];
    if (t < NBLK) blocksum[t] = add + x - v;   // exclusive
}

// ------------------------- multi-block scan (3/3): rowptr + cursor + dinv
__global__ __launch_bounds__(256)
void k_scan3(const u64* __restrict__ hist, const int* __restrict__ blocksum,
             float* __restrict__ dinv, int* __restrict__ cursor,
             int* __restrict__ rowptr) {
    int i = blockIdx.x * 256 + threadIdx.x;
    int t = threadIdx.x, lane = t & 63, w = t >> 6;
    u64 hv = (i < N_NODES) ? hist[i] : 0ull;
    int v = (int)(hv >> FX_BITS);
    int x = v;
#pragma unroll
    for (int off = 1; off < 64; off <<= 1) {
        int y = __shfl_up(x, off, 64);
        if (lane >= off) x += y;
    }
    __shared__ int ws[4];
    if (lane == 63) ws[w] = x;
    __syncthreads();
    int add = blocksum[blockIdx.x];
    for (int j = 0; j < w; ++j) add += ws[j];
    int excl = add + x - v;
    if (i < N_NODES) {
        rowptr[i] = excl;
        cursor[i] = excl;
        // deg = 1 (self-loop) + fixed-point weight sum
        float dg = 1.0f + (float)((double)(hv & FX_MASK) * (1.0 / FX_SCALE));
        dinv[i] = rsqrtf(dg);                  // dg >= 1 always
        if (i == N_NODES - 1) rowptr[N_NODES] = N_EDGES;
    }
}

// ----------------------------------------------- scatter edges into CSR(dst)
__global__ void k_scatter(const int* __restrict__ src, const int* __restrict__ dst,
                          const float* __restrict__ w, const float* __restrict__ dinv,
                          int* __restrict__ cursor, int2* __restrict__ edat) {
    int e = blockIdx.x * 256 + threadIdx.x;
    if (e < N_EDGES) {
        int s = src[e], d = dst[e];
        int pos = atomicAdd(&cursor[d], 1);
        float c = dinv[s] * w[e] * dinv[d];
        edat[pos] = make_int2(s, __float_as_int(c));
    }
}

// --------------------------------- fp32 GEMM  H = X @ W, H stored as fp16
__global__ __launch_bounds__(256)
void k_gemm(const float* __restrict__ X, const float* __restrict__ W,
            u16* __restrict__ H) {
    __shared__ float Wl[64][128];   // 32 KB
    __shared__ float Xl[64][68];    // 17.4 KB (pad 64->68)
    int t = threadIdx.x;
    int rb = blockIdx.x * 64;
    int colb = (t & 31) * 4;        // output col base
    int rg = t >> 5;                // row group 0..7

    float acc[8][4] = {};

    for (int k0 = 0; k0 < 128; k0 += 64) {
        {
            const float4* Wg = (const float4*)(W + k0 * 128);
            float4* Ws = (float4*)&Wl[0][0];
#pragma unroll
            for (int j = 0; j < 8; ++j) Ws[t + 256 * j] = Wg[t + 256 * j];
        }
        {
#pragma unroll
            for (int j = 0; j < 4; ++j) {
                int idx = t + 256 * j;          // 0..1023
                int r = idx >> 4;               // 16 float4 per row
                int c4 = (idx & 15) * 4;
                int row = rb + r;
                float4 v = make_float4(0.f, 0.f, 0.f, 0.f);
                if (row < N_NODES) v = *(const float4*)(X + (size_t)row * FDIM + k0 + c4);
                *(float4*)&Xl[r][c4] = v;
            }
        }
        __syncthreads();
#pragma unroll
        for (int k = 0; k < 64; k += 4) {
            float4 wv0 = *(const float4*)&Wl[k + 0][colb];
            float4 wv1 = *(const float4*)&Wl[k + 1][colb];
            float4 wv2 = *(const float4*)&Wl[k + 2][colb];
            float4 wv3 = *(const float4*)&Wl[k + 3][colb];
#pragma unroll
            for (int r = 0; r < 8; ++r) {
                float4 xv = *(const float4*)&Xl[rg * 8 + r][k];
                acc[r][0] += xv.x * wv0.x; acc[r][1] += xv.x * wv0.y;
                acc[r][2] += xv.x * wv0.z; acc[r][3] += xv.x * wv0.w;
                acc[r][0] += xv.y * wv1.x; acc[r][1] += xv.y * wv1.y;
                acc[r][2] += xv.y * wv1.z; acc[r][3] += xv.y * wv1.w;
                acc[r][0] += xv.z * wv2.x; acc[r][1] += xv.z * wv2.y;
                acc[r][2] += xv.z * wv2.z; acc[r][3] += xv.z * wv2.w;
                acc[r][0] += xv.w * wv3.x; acc[r][1] += xv.w * wv3.y;
                acc[r][2] += xv.w * wv3.z; acc[r][3] += xv.w * wv3.w;
            }
        }
        __syncthreads();
    }
#pragma unroll
    for (int r = 0; r < 8; ++r) {
        int row = rb + rg * 8 + r;
        if (row < N_NODES) {
            uint2 pv;
            pv.x = pack_h2(acc[r][0], acc[r][1]);
            pv.y = pack_h2(acc[r][2], acc[r][3]);
            *(uint2*)(H + (size_t)row * FDIM + colb) = pv;
        }
    }
}

// --- aggregation (fp16 H gather) + bias + L2-normalize + ReLU (1 wave/node)
__global__ __launch_bounds__(256)
void k_agg(const u16* __restrict__ H, const int* __restrict__ rowptr,
           const int2* __restrict__ edat, const float* __restrict__ dinv,
           const float* __restrict__ bias, float* __restrict__ out) {
    int wid  = threadIdx.x >> 6;
    int lane = threadIdx.x & 63;
    int node = blockIdx.x * 4 + wid;
    if (node >= N_NODES) return;

    const u32* H2 = (const u32*)H;   // 2 fp16 per u32; row stride 64 u32
    float di = dinv[node];
    float2 acc;
    {   // self loop: coef = dinv[i]*1*dinv[i]
        float2 hv = unpack_h2(H2[(size_t)node * 64 + lane]);
        float cs = di * di;
        acc.x = cs * hv.x; acc.y = cs * hv.y;
    }
    int e = rowptr[node], eend = rowptr[node + 1];
    for (; e + 4 <= eend; e += 4) {
        int2 e0 = edat[e], e1 = edat[e + 1], e2 = edat[e + 2], e3 = edat[e + 3];
        u32 r0 = H2[(size_t)e0.x * 64 + lane];
        u32 r1 = H2[(size_t)e1.x * 64 + lane];
        u32 r2 = H2[(size_t)e2.x * 64 + lane];
        u32 r3 = H2[(size_t)e3.x * 64 + lane];
        float2 v0 = unpack_h2(r0), v1 = unpack_h2(r1);
        float2 v2 = unpack_h2(r2), v3 = unpack_h2(r3);
        float c0 = __int_as_float(e0.y), c1 = __int_as_float(e1.y);
        float c2 = __int_as_float(e2.y), c3 = __int_as_float(e3.y);
        acc.x += c0 * v0.x; acc.y += c0 * v0.y;
        acc.x += c1 * v1.x; acc.y += c1 * v1.y;
        acc.x += c2 * v2.x; acc.y += c2 * v2.y;
        acc.x += c3 * v3.x; acc.y += c3 * v3.y;
    }
    for (; e < eend; ++e) {
        int2 ed = edat[e];
        float c = __int_as_float(ed.y);
        float2 v = unpack_h2(H2[(size_t)ed.x * 64 + lane]);
        acc.x += c * v.x; acc.y += c * v.y;
    }
    acc.x += bias[lane * 2];
    acc.y += bias[lane * 2 + 1];

    float ss = acc.x * acc.x + acc.y * acc.y;
#pragma unroll
    for (int off = 32; off >= 1; off >>= 1) ss += __shfl_xor(ss, off, 64);
    float n = sqrtf(ss);
    float inv = 1.0f / fmaxf(n, 1e-12f);
    float ox = fmaxf(acc.x * inv, 0.0f);
    float oy = fmaxf(acc.y * inv, 0.0f);
    *(float2*)(out + (size_t)node * FDIM + lane * 2) = make_float2(ox, oy);
}

// ------------------------------------- final linear: concat(o1,o2,o3) @ Wlin
__global__ __launch_bounds__(256)
void k_final(const float* __restrict__ o1, const float* __restrict__ o2,
             const float* __restrict__ o3, const float* __restrict__ Wlin,
             const float* __restrict__ blin, float* __restrict__ out) {
    __shared__ float Wt[C_OUT][384];   // transposed: Wt[c][f]
    __shared__ float bl[C_OUT];
    int t = threadIdx.x;
    for (int i = t; i < 384 * C_OUT; i += 256) {
        int f = i / C_OUT, c = i % C_OUT;
        Wt[c][f] = Wlin[i];
    }
    if (t < C_OUT) bl[t] = blin[t];
    __syncthreads();

    int wid = t >> 6, lane = t & 63;
    int node = blockIdx.x * 4 + wid;
    if (node >= N_NODES) return;

    size_t base = (size_t)node * FDIM;
    float v0 = o1[base + lane],       v1 = o1[base + 64 + lane];
    float v2 = o2[base + lane],       v3 = o2[base + 64 + lane];
    float v4 = o3[base + lane],       v5 = o3[base + 64 + lane];

    float acc[C_OUT];
#pragma unroll
    for (int c = 0; c < C_OUT; ++c) {
        acc[c] = v0 * Wt[c][lane]       + v1 * Wt[c][64 + lane]
               + v2 * Wt[c][128 + lane] + v3 * Wt[c][192 + lane]
               + v4 * Wt[c][256 + lane] + v5 * Wt[c][320 + lane];
    }
#pragma unroll
    for (int c = 0; c < C_OUT; ++c)
#pragma unroll
        for (int off = 32; off >= 1; off >>= 1) acc[c] += __shfl_xor(acc[c], off, 64);
    if (lane == 0) {
#pragma unroll
        for (int c = 0; c < C_OUT; ++c)
            out[(size_t)node * C_OUT + c] = acc[c] + bl[c];
    }
}

// -------------------------------------------------------------------- launch
extern "C" void kernel_launch(void* const* d_in, const int* in_sizes, int n_in,
                              void* d_out, int out_size, void* d_ws, size_t ws_size,
                              hipStream_t stream) {
    const float* x  = (const float*)d_in[0];
    const int*   ei = (const int*)d_in[1];
    const float* ew = (const float*)d_in[2];
    const float* W1 = (const float*)d_in[3];
    const float* b1 = (const float*)d_in[4];
    const float* W2 = (const float*)d_in[5];
    const float* b2 = (const float*)d_in[6];
    const float* W3 = (const float*)d_in[7];
    const float* b3 = (const float*)d_in[8];
    const float* Wl = (const float*)d_in[9];
    const float* bl = (const float*)d_in[10];
    float* out = (float*)d_out;

    const int* srcI = ei;             // edge_index[0]
    const int* dstI = ei + N_EDGES;   // edge_index[1]

    char* p = (char*)d_ws;
    auto alloc = [&](size_t bytes) {
        char* r = p;
        p += (bytes + 255) & ~(size_t)255;
        return r;
    };
    u64*   hist   = (u64*)  alloc((size_t)N_NODES * 8);
    float* dinv   = (float*)alloc((size_t)N_NODES * 4);
    int*   cursor = (int*)  alloc((size_t)N_NODES * 4);
    int*   rowptr = (int*)  alloc((size_t)(N_NODES + 1) * 4);
    int*   bsum   = (int*)  alloc((size_t)NBLK * 4);
    int2*  edat   = (int2*) alloc((size_t)N_EDGES * 8);
    u16*   h      = (u16*)  alloc((size_t)N_NODES * FDIM * 2);
    float* o1     = (float*)alloc((size_t)N_NODES * FDIM * 4);
    float* o2     = (float*)alloc((size_t)N_NODES * FDIM * 4);
    float* o3     = (float*)alloc((size_t)N_NODES * FDIM * 4);

    k_init   <<<NBLK, 256, 0, stream>>>(hist);
    k_hist   <<<(N_EDGES + 255) / 256, 256, 0, stream>>>(dstI, ew, hist);
    k_scan1  <<<NBLK, 256, 0, stream>>>(hist, bsum);
    k_scan2  <<<1, 256, 0, stream>>>(bsum);
    k_scan3  <<<NBLK, 256, 0, stream>>>(hist, bsum, dinv, cursor, rowptr);
    k_scatter<<<(N_EDGES + 255) / 256, 256, 0, stream>>>(srcI, dstI, ew, dinv, cursor, edat);

    const float* Wmats[3] = {W1, W2, W3};
    const float* bvecs[3] = {b1, b2, b3};
    float* outs[3] = {o1, o2, o3};
    const float* in = x;
    for (int l = 0; l < 3; ++l) {
        k_gemm<<<(N_NODES + 63) / 64, 256, 0, stream>>>(in, Wmats[l], h);
        k_agg <<<N_NODES / 4, 256, 0, stream>>>(h, rowptr, edat, dinv, bvecs[l], outs[l]);
        in = outs[l];
    }
    k_final<<<N_NODES / 4, 256, 0, stream>>>(o1, o2, o3, Wl, bl, out);
}

// Round 9
// 597.753 us; speedup vs baseline: 1.6963x; 1.0122x over previous
//
#include <hip/hip_runtime.h>
#include <hip/hip_fp16.h>

#define N_NODES 50000
#define N_EDGES 1600000
#define FDIM    128
#define C_OUT   10
#define NBLK    ((N_NODES + 255) / 256)   // 196

typedef unsigned long long u64;
typedef unsigned int u32;
typedef unsigned short u16;
#define FX_BITS 44
#define FX_MASK ((1ull << FX_BITS) - 1)
#define FX_SCALE 4294967296.0   // 2^32

__device__ __forceinline__ u32 pack_h2(float a, float b) {
    __half2 h = __floats2half2_rn(a, b);
    return *(u32*)&h;
}
__device__ __forceinline__ float2 unpack_h2(u32 u) {
    __half2 h = *(__half2*)&u;
    return __half22float2(h);
}
// edge record: bits[31:15] = src (17b), bits[14:0] = fp16(coef) (sign always 0)
__device__ __forceinline__ u32 pack_edge(int s, float c) {
    __half h = __float2half_rn(c);
    u16 hb = *(u16*)&h;                 // bit15 == 0 (c >= 0)
    return ((u32)s << 15) | (u32)hb;
}
__device__ __forceinline__ int edge_src(u32 u) { return (int)(u >> 15); }
__device__ __forceinline__ float edge_coef(u32 u) {
    u16 hb = (u16)(u & 0x7FFFu);
    __half h = *(__half*)&hb;
    return __half2float(h);
}

// ---------------------------------------------------------------- init
__global__ void k_init(u64* __restrict__ hist) {
    int i = blockIdx.x * 256 + threadIdx.x;
    if (i < N_NODES) hist[i] = 0ull;
}

// ----------------- degree + dst histogram: ONE packed 64-bit atomic per edge
// bits [63:44] = count, bits [43:0] = sum(w) in 2^32 fixed point
__global__ void k_hist(const int* __restrict__ dst, const float* __restrict__ w,
                       u64* __restrict__ hist) {
    int e = blockIdx.x * 256 + threadIdx.x;
    if (e < N_EDGES) {
        u64 fx = (u64)((double)w[e] * FX_SCALE + 0.5);
        u64 packed = (1ull << FX_BITS) | fx;
        atomicAdd(&hist[dst[e]], packed);
    }
}

// ---------------------------------------------------- multi-block scan (1/3)
__global__ __launch_bounds__(256)
void k_scan1(const u64* __restrict__ hist, int* __restrict__ blocksum) {
    int i = blockIdx.x * 256 + threadIdx.x;
    int v = (i < N_NODES) ? (int)(hist[i] >> FX_BITS) : 0;
#pragma unroll
    for (int off = 32; off >= 1; off >>= 1) v += __shfl_xor(v, off, 64);
    __shared__ int ws[4];
    if ((threadIdx.x & 63) == 0) ws[threadIdx.x >> 6] = v;
    __syncthreads();
    if (threadIdx.x == 0) blocksum[blockIdx.x] = ws[0] + ws[1] + ws[2] + ws[3];
}

// ---------------------------------------------------- multi-block scan (2/3)
__global__ __launch_bounds__(256)
void k_scan2(int* __restrict__ blocksum) {
    int t = threadIdx.x, lane = t & 63, w = t >> 6;
    int v = (t < NBLK) ? blocksum[t] : 0;
    int x = v;
#pragma unroll
    for (int off = 1; off < 64; off <<= 1) {
        int y = __shfl_up(x, off, 64);
        if (lane >= off) x += y;
    }
    __shared__ int ws[4];
    if (lane == 63) ws[w] = x;
    __syncthreads();
    int add = 0;
    for (int j = 0; j < w; ++j) add += ws[j];
    if (t < NBLK) blocksum[t] = add + x - v;   // exclusive
}

// ------------------------- multi-block scan (3/3): rowptr + cursor + dinv
__global__ __launch_bounds__(256)
void k_scan3(const u64* __restrict__ hist, const int* __restrict__ blocksum,
             float* __restrict__ dinv, int* __restrict__ cursor,
             int* __restrict__ rowptr) {
    int i = blockIdx.x * 256 + threadIdx.x;
    int t = threadIdx.x, lane = t & 63, w = t >> 6;
    u64 hv = (i < N_NODES) ? hist[i] : 0ull;
    int v = (int)(hv >> FX_BITS);
    int x = v;
#pragma unroll
    for (int off = 1; off < 64; off <<= 1) {
        int y = __shfl_up(x, off, 64);
        if (lane >= off) x += y;
    }
    __shared__ int ws[4];
    if (lane == 63) ws[w] = x;
    __syncthreads();
    int add = blocksum[blockIdx.x];
    for (int j = 0; j < w; ++j) add += ws[j];
    int excl = add + x - v;
    if (i < N_NODES) {
        rowptr[i] = excl;
        cursor[i] = excl;
        // deg = 1 (self-loop) + fixed-point weight sum
        float dg = 1.0f + (float)((double)(hv & FX_MASK) * (1.0 / FX_SCALE));
        dinv[i] = rsqrtf(dg);                  // dg >= 1 always
        if (i == N_NODES - 1) rowptr[N_NODES] = N_EDGES;
    }
}

// --------------------- scatter edges into CSR(dst), 4-byte packed records
__global__ void k_scatter(const int* __restrict__ src, const int* __restrict__ dst,
                          const float* __restrict__ w, const float* __restrict__ dinv,
                          int* __restrict__ cursor, u32* __restrict__ edat) {
    int e = blockIdx.x * 256 + threadIdx.x;
    if (e < N_EDGES) {
        int s = src[e], d = dst[e];
        int pos = atomicAdd(&cursor[d], 1);
        float c = dinv[s] * w[e] * dinv[d];
        edat[pos] = pack_edge(s, c);
    }
}

// --------------------------------- fp32 GEMM  H = X @ W, H stored as fp16
__global__ __launch_bounds__(256)
void k_gemm(const float* __restrict__ X, const float* __restrict__ W,
            u16* __restrict__ H) {
    __shared__ float Wl[64][128];   // 32 KB
    __shared__ float Xl[64][68];    // 17.4 KB (pad 64->68)
    int t = threadIdx.x;
    int rb = blockIdx.x * 64;
    int colb = (t & 31) * 4;        // output col base
    int rg = t >> 5;                // row group 0..7

    float acc[8][4] = {};

    for (int k0 = 0; k0 < 128; k0 += 64) {
        {
            const float4* Wg = (const float4*)(W + k0 * 128);
            float4* Ws = (float4*)&Wl[0][0];
#pragma unroll
            for (int j = 0; j < 8; ++j) Ws[t + 256 * j] = Wg[t + 256 * j];
        }
        {
#pragma unroll
            for (int j = 0; j < 4; ++j) {
                int idx = t + 256 * j;          // 0..1023
                int r = idx >> 4;               // 16 float4 per row
                int c4 = (idx & 15) * 4;
                int row = rb + r;
                float4 v = make_float4(0.f, 0.f, 0.f, 0.f);
                if (row < N_NODES) v = *(const float4*)(X + (size_t)row * FDIM + k0 + c4);
                *(float4*)&Xl[r][c4] = v;
            }
        }
        __syncthreads();
#pragma unroll
        for (int k = 0; k < 64; k += 4) {
            float4 wv0 = *(const float4*)&Wl[k + 0][colb];
            float4 wv1 = *(const float4*)&Wl[k + 1][colb];
            float4 wv2 = *(const float4*)&Wl[k + 2][colb];
            float4 wv3 = *(const float4*)&Wl[k + 3][colb];
#pragma unroll
            for (int r = 0; r < 8; ++r) {
                float4 xv = *(const float4*)&Xl[rg * 8 + r][k];
                acc[r][0] += xv.x * wv0.x; acc[r][1] += xv.x * wv0.y;
                acc[r][2] += xv.x * wv0.z; acc[r][3] += xv.x * wv0.w;
                acc[r][0] += xv.y * wv1.x; acc[r][1] += xv.y * wv1.y;
                acc[r][2] += xv.y * wv1.z; acc[r][3] += xv.y * wv1.w;
                acc[r][0] += xv.z * wv2.x; acc[r][1] += xv.z * wv2.y;
                acc[r][2] += xv.z * wv2.z; acc[r][3] += xv.z * wv2.w;
                acc[r][0] += xv.w * wv3.x; acc[r][1] += xv.w * wv3.y;
                acc[r][2] += xv.w * wv3.z; acc[r][3] += xv.w * wv3.w;
            }
        }
        __syncthreads();
    }
#pragma unroll
    for (int r = 0; r < 8; ++r) {
        int row = rb + rg * 8 + r;
        if (row < N_NODES) {
            uint2 pv;
            pv.x = pack_h2(acc[r][0], acc[r][1]);
            pv.y = pack_h2(acc[r][2], acc[r][3]);
            *(uint2*)(H + (size_t)row * FDIM + colb) = pv;
        }
    }
}

// --- aggregation (fp16 H gather) + bias + L2-normalize + ReLU (1 wave/node)
__global__ __launch_bounds__(256)
void k_agg(const u16* __restrict__ H, const int* __restrict__ rowptr,
           const u32* __restrict__ edat, const float* __restrict__ dinv,
           const float* __restrict__ bias, float* __restrict__ out) {
    int wid  = threadIdx.x >> 6;
    int lane = threadIdx.x & 63;
    int node = blockIdx.x * 4 + wid;
    if (node >= N_NODES) return;

    const u32* H2 = (const u32*)H;   // 2 fp16 per u32; row stride 64 u32
    float di = dinv[node];
    float2 acc;
    {   // self loop: coef = dinv[i]*1*dinv[i]
        float2 hv = unpack_h2(H2[(size_t)node * 64 + lane]);
        float cs = di * di;
        acc.x = cs * hv.x; acc.y = cs * hv.y;
    }
    int e = rowptr[node], eend = rowptr[node + 1];
    for (; e + 4 <= eend; e += 4) {
        u32 e0 = edat[e], e1 = edat[e + 1], e2 = edat[e + 2], e3 = edat[e + 3];
        u32 r0 = H2[(size_t)edge_src(e0) * 64 + lane];
        u32 r1 = H2[(size_t)edge_src(e1) * 64 + lane];
        u32 r2 = H2[(size_t)edge_src(e2) * 64 + lane];
        u32 r3 = H2[(size_t)edge_src(e3) * 64 + lane];
        float2 v0 = unpack_h2(r0), v1 = unpack_h2(r1);
        float2 v2 = unpack_h2(r2), v3 = unpack_h2(r3);
        float c0 = edge_coef(e0), c1 = edge_coef(e1);
        float c2 = edge_coef(e2), c3 = edge_coef(e3);
        acc.x += c0 * v0.x; acc.y += c0 * v0.y;
        acc.x += c1 * v1.x; acc.y += c1 * v1.y;
        acc.x += c2 * v2.x; acc.y += c2 * v2.y;
        acc.x += c3 * v3.x; acc.y += c3 * v3.y;
    }
    for (; e < eend; ++e) {
        u32 ed = edat[e];
        float c = edge_coef(ed);
        float2 v = unpack_h2(H2[(size_t)edge_src(ed) * 64 + lane]);
        acc.x += c * v.x; acc.y += c * v.y;
    }
    acc.x += bias[lane * 2];
    acc.y += bias[lane * 2 + 1];

    float ss = acc.x * acc.x + acc.y * acc.y;
#pragma unroll
    for (int off = 32; off >= 1; off >>= 1) ss += __shfl_xor(ss, off, 64);
    float n = sqrtf(ss);
    float inv = 1.0f / fmaxf(n, 1e-12f);
    float ox = fmaxf(acc.x * inv, 0.0f);
    float oy = fmaxf(acc.y * inv, 0.0f);
    *(float2*)(out + (size_t)node * FDIM + lane * 2) = make_float2(ox, oy);
}

// ------------------------------------- final linear: concat(o1,o2,o3) @ Wlin
__global__ __launch_bounds__(256)
void k_final(const float* __restrict__ o1, const float* __restrict__ o2,
             const float* __restrict__ o3, const float* __restrict__ Wlin,
             const float* __restrict__ blin, float* __restrict__ out) {
    __shared__ float Wt[C_OUT][384];   // transposed: Wt[c][f]
    __shared__ float bl[C_OUT];
    int t = threadIdx.x;
    for (int i = t; i < 384 * C_OUT; i += 256) {
        int f = i / C_OUT, c = i % C_OUT;
        Wt[c][f] = Wlin[i];
    }
    if (t < C_OUT) bl[t] = blin[t];
    __syncthreads();

    int wid = t >> 6, lane = t & 63;
    int node = blockIdx.x * 4 + wid;
    if (node >= N_NODES) return;

    size_t base = (size_t)node * FDIM;
    float v0 = o1[base + lane],       v1 = o1[base + 64 + lane];
    float v2 = o2[base + lane],       v3 = o2[base + 64 + lane];
    float v4 = o3[base + lane],       v5 = o3[base + 64 + lane];

    float acc[C_OUT];
#pragma unroll
    for (int c = 0; c < C_OUT; ++c) {
        acc[c] = v0 * Wt[c][lane]       + v1 * Wt[c][64 + lane]
               + v2 * Wt[c][128 + lane] + v3 * Wt[c][192 + lane]
               + v4 * Wt[c][256 + lane] + v5 * Wt[c][320 + lane];
    }
#pragma unroll
    for (int c = 0; c < C_OUT; ++c)
#pragma unroll
        for (int off = 32; off >= 1; off >>= 1) acc[c] += __shfl_xor(acc[c], off, 64);
    if (lane == 0) {
#pragma unroll
        for (int c = 0; c < C_OUT; ++c)
            out[(size_t)node * C_OUT + c] = acc[c] + bl[c];
    }
}

// -------------------------------------------------------------------- launch
extern "C" void kernel_launch(void* const* d_in, const int* in_sizes, int n_in,
                              void* d_out, int out_size, void* d_ws, size_t ws_size,
                              hipStream_t stream) {
    const float* x  = (const float*)d_in[0];
    const int*   ei = (const int*)d_in[1];
    const float* ew = (const float*)d_in[2];
    const float* W1 = (const float*)d_in[3];
    const float* b1 = (const float*)d_in[4];
    const float* W2 = (const float*)d_in[5];
    const float* b2 = (const float*)d_in[6];
    const float* W3 = (const float*)d_in[7];
    const float* b3 = (const float*)d_in[8];
    const float* Wl = (const float*)d_in[9];
    const float* bl = (const float*)d_in[10];
    float* out = (float*)d_out;

    const int* srcI = ei;             // edge_index[0]
    const int* dstI = ei + N_EDGES;   // edge_index[1]

    char* p = (char*)d_ws;
    auto alloc = [&](size_t bytes) {
        char* r = p;
        p += (bytes + 255) & ~(size_t)255;
        return r;
    };
    u64*   hist   = (u64*)  alloc((size_t)N_NODES * 8);
    float* dinv   = (float*)alloc((size_t)N_NODES * 4);
    int*   cursor = (int*)  alloc((size_t)N_NODES * 4);
    int*   rowptr = (int*)  alloc((size_t)(N_NODES + 1) * 4);
    int*   bsum   = (int*)  alloc((size_t)NBLK * 4);
    u32*   edat   = (u32*)  alloc((size_t)N_EDGES * 4);
    u16*   h      = (u16*)  alloc((size_t)N_NODES * FDIM * 2);
    float* o1     = (float*)alloc((size_t)N_NODES * FDIM * 4);
    float* o2     = (float*)alloc((size_t)N_NODES * FDIM * 4);
    float* o3     = (float*)alloc((size_t)N_NODES * FDIM * 4);

    k_init   <<<NBLK, 256, 0, stream>>>(hist);
    k_hist   <<<(N_EDGES + 255) / 256, 256, 0, stream>>>(dstI, ew, hist);
    k_scan1  <<<NBLK, 256, 0, stream>>>(hist, bsum);
    k_scan2  <<<1, 256, 0, stream>>>(bsum);
    k_scan3  <<<NBLK, 256, 0, stream>>>(hist, bsum, dinv, cursor, rowptr);
    k_scatter<<<(N_EDGES + 255) / 256, 256, 0, stream>>>(srcI, dstI, ew, dinv, cursor, edat);

    const float* Wmats[3] = {W1, W2, W3};
    const float* bvecs[3] = {b1, b2, b3};
    float* outs[3] = {o1, o2, o3};
    const float* in = x;
    for (int l = 0; l < 3; ++l) {
        k_gemm<<<(N_NODES + 63) / 64, 256, 0, stream>>>(in, Wmats[l], h);
        k_agg <<<N_NODES / 4, 256, 0, stream>>>(h, rowptr, edat, dinv, bvecs[l], outs[l]);
        in = outs[l];
    }
    k_final<<<N_NODES / 4, 256, 0, stream>>>(o1, o2, o3, Wl, bl, out);
}

// Round 12
// 592.453 us; speedup vs baseline: 1.7114x; 1.0089x over previous
//
#include <hip/hip_runtime.h>
#include <hip/hip_fp16.h>

#define N_NODES 50000
#define N_EDGES 1600000
#define FDIM    128
#define C_OUT   10
#define NBLK    ((N_NODES + 255) / 256)   // 196

typedef unsigned long long u64;
typedef unsigned int u32;
typedef unsigned short u16;
#define FX_BITS 44
#define FX_MASK ((1ull << FX_BITS) - 1)
#define FX_SCALE 4294967296.0   // 2^32

__device__ __forceinline__ u32 pack_h2(float a, float b) {
    __half2 h = __floats2half2_rn(a, b);
    return *(u32*)&h;
}
__device__ __forceinline__ float2 unpack_h2(u32 u) {
    __half2 h = *(__half2*)&u;
    return __half22float2(h);
}
// edge record: bits[31:15] = src (17b), bits[14:0] = fp16(coef) (sign always 0)
__device__ __forceinline__ u32 pack_edge(int s, float c) {
    __half h = __float2half_rn(c);
    u16 hb = *(u16*)&h;                 // bit15 == 0 (c >= 0)
    return ((u32)s << 15) | (u32)hb;
}
__device__ __forceinline__ int edge_src(u32 u) { return (int)(u >> 15); }
__device__ __forceinline__ float edge_coef(u32 u) {
    u16 hb = (u16)(u & 0x7FFFu);
    __half h = *(__half*)&hb;
    return __half2float(h);
}

// ---------------------------------------------------------------- init
__global__ void k_init(u64* __restrict__ hist) {
    int i = blockIdx.x * 256 + threadIdx.x;
    if (i < N_NODES) hist[i] = 0ull;
}

// ----------------- degree + dst histogram: ONE packed 64-bit atomic per edge
__global__ void k_hist(const int* __restrict__ dst, const float* __restrict__ w,
                       u64* __restrict__ hist) {
    int e = blockIdx.x * 256 + threadIdx.x;
    if (e < N_EDGES) {
        u64 fx = (u64)((double)w[e] * FX_SCALE + 0.5);
        u64 packed = (1ull << FX_BITS) | fx;
        atomicAdd(&hist[dst[e]], packed);
    }
}

// ---------------------------------------------------- multi-block scan (1/3)
__global__ __launch_bounds__(256)
void k_scan1(const u64* __restrict__ hist, int* __restrict__ blocksum) {
    int i = blockIdx.x * 256 + threadIdx.x;
    int v = (i < N_NODES) ? (int)(hist[i] >> FX_BITS) : 0;
#pragma unroll
    for (int off = 32; off >= 1; off >>= 1) v += __shfl_xor(v, off, 64);
    __shared__ int ws[4];
    if ((threadIdx.x & 63) == 0) ws[threadIdx.x >> 6] = v;
    __syncthreads();
    if (threadIdx.x == 0) blocksum[blockIdx.x] = ws[0] + ws[1] + ws[2] + ws[3];
}

// ---------------------------------------------------- multi-block scan (2/3)
__global__ __launch_bounds__(256)
void k_scan2(int* __restrict__ blocksum) {
    int t = threadIdx.x, lane = t & 63, w = t >> 6;
    int v = (t < NBLK) ? blocksum[t] : 0;
    int x = v;
#pragma unroll
    for (int off = 1; off < 64; off <<= 1) {
        int y = __shfl_up(x, off, 64);
        if (lane >= off) x += y;
    }
    __shared__ int ws[4];
    if (lane == 63) ws[w] = x;
    __syncthreads();
    int add = 0;
    for (int j = 0; j < w; ++j) add += ws[j];
    if (t < NBLK) blocksum[t] = add + x - v;   // exclusive
}

// ------------------------- multi-block scan (3/3): rowptr + cursor + dinv
__global__ __launch_bounds__(256)
void k_scan3(const u64* __restrict__ hist, const int* __restrict__ blocksum,
             float* __restrict__ dinv, int* __restrict__ cursor,
             int* __restrict__ rowptr) {
    int i = blockIdx.x * 256 + threadIdx.x;
    int t = threadIdx.x, lane = t & 63, w = t >> 6;
    u64 hv = (i < N_NODES) ? hist[i] : 0ull;
    int v = (int)(hv >> FX_BITS);
    int x = v;
#pragma unroll
    for (int off = 1; off < 64; off <<= 1) {
        int y = __shfl_up(x, off, 64);
        if (lane >= off) x += y;
    }
    __shared__ int ws[4];
    if (lane == 63) ws[w] = x;
    __syncthreads();
    int add = blocksum[blockIdx.x];
    for (int j = 0; j < w; ++j) add += ws[j];
    int excl = add + x - v;
    if (i < N_NODES) {
        rowptr[i] = excl;
        cursor[i] = excl;
        float dg = 1.0f + (float)((double)(hv & FX_MASK) * (1.0 / FX_SCALE));
        dinv[i] = rsqrtf(dg);                  // dg >= 1 always
        if (i == N_NODES - 1) rowptr[N_NODES] = N_EDGES;
    }
}

// --------------------- scatter edges into CSR(dst), 4-byte packed records
__global__ void k_scatter(const int* __restrict__ src, const int* __restrict__ dst,
                          const float* __restrict__ w, const float* __restrict__ dinv,
                          int* __restrict__ cursor, u32* __restrict__ edat) {
    int e = blockIdx.x * 256 + threadIdx.x;
    if (e < N_EDGES) {
        int s = src[e], d = dst[e];
        int pos = atomicAdd(&cursor[d], 1);
        float c = dinv[s] * w[e] * dinv[d];
        __builtin_nontemporal_store(pack_edge(s, c), &edat[pos]);
    }
}

// ------------------- fp32-accum GEMM  H = X @ W, H stored fp16; X fp32|fp16
template<typename TIN>
__global__ __launch_bounds__(256)
void k_gemm(const TIN* __restrict__ X, const float* __restrict__ W,
            u16* __restrict__ H) {
    __shared__ float Wl[64][128];   // 32 KB
    __shared__ float Xl[64][68];    // 17.4 KB (pad 64->68)
    int t = threadIdx.x;
    int rb = blockIdx.x * 64;
    int colb = (t & 31) * 4;        // output col base
    int rg = t >> 5;                // row group 0..7

    float acc[8][4] = {};

    for (int k0 = 0; k0 < 128; k0 += 64) {
        {
            const float4* Wg = (const float4*)(W + k0 * 128);
            float4* Ws = (float4*)&Wl[0][0];
#pragma unroll
            for (int j = 0; j < 8; ++j) Ws[t + 256 * j] = Wg[t + 256 * j];
        }
        {
#pragma unroll
            for (int j = 0; j < 4; ++j) {
                int idx = t + 256 * j;          // 0..1023
                int r = idx >> 4;               // 16 float4-groups per row
                int c4 = (idx & 15) * 4;
                int row = rb + r;
                float4 v = make_float4(0.f, 0.f, 0.f, 0.f);
                if (row < N_NODES) {
                    if constexpr (sizeof(TIN) == 4) {
                        v = *(const float4*)(X + (size_t)row * FDIM + k0 + c4);
                    } else {
                        uint2 pv = *(const uint2*)(X + (size_t)row * FDIM + k0 + c4);
                        float2 lo = unpack_h2(pv.x), hi = unpack_h2(pv.y);
                        v = make_float4(lo.x, lo.y, hi.x, hi.y);
                    }
                }
                *(float4*)&Xl[r][c4] = v;
            }
        }
        __syncthreads();
#pragma unroll
        for (int k = 0; k < 64; k += 4) {
            float4 wv0 = *(const float4*)&Wl[k + 0][colb];
            float4 wv1 = *(const float4*)&Wl[k + 1][colb];
            float4 wv2 = *(const float4*)&Wl[k + 2][colb];
            float4 wv3 = *(const float4*)&Wl[k + 3][colb];
#pragma unroll
            for (int r = 0; r < 8; ++r) {
                float4 xv = *(const float4*)&Xl[rg * 8 + r][k];
                acc[r][0] += xv.x * wv0.x; acc[r][1] += xv.x * wv0.y;
                acc[r][2] += xv.x * wv0.z; acc[r][3] += xv.x * wv0.w;
                acc[r][0] += xv.y * wv1.x; acc[r][1] += xv.y * wv1.y;
                acc[r][2] += xv.y * wv1.z; acc[r][3] += xv.y * wv1.w;
                acc[r][0] += xv.z * wv2.x; acc[r][1] += xv.z * wv2.y;
                acc[r][2] += xv.z * wv2.z; acc[r][3] += xv.z * wv2.w;
                acc[r][0] += xv.w * wv3.x; acc[r][1] += xv.w * wv3.y;
                acc[r][2] += xv.w * wv3.z; acc[r][3] += xv.w * wv3.w;
            }
        }
        __syncthreads();
    }
#pragma unroll
    for (int r = 0; r < 8; ++r) {
        int row = rb + rg * 8 + r;
        if (row < N_NODES) {
            uint2 pv;
            pv.x = pack_h2(acc[r][0], acc[r][1]);
            pv.y = pack_h2(acc[r][2], acc[r][3]);
            *(uint2*)(H + (size_t)row * FDIM + colb) = pv;
        }
    }
}

// --- aggregation (fp16 H gather) + bias + L2-norm + ReLU; out fp16-packed
__global__ __launch_bounds__(256)
void k_agg(const u16* __restrict__ H, const int* __restrict__ rowptr,
           const u32* __restrict__ edat, const float* __restrict__ dinv,
           const float* __restrict__ bias, u32* __restrict__ out) {
    int wid  = threadIdx.x >> 6;
    int lane = threadIdx.x & 63;
    int node = blockIdx.x * 4 + wid;
    if (node >= N_NODES) return;

    const u32* H2 = (const u32*)H;   // 2 fp16 per u32; row stride 64 u32
    float di = dinv[node];
    float2 acc;
    {   // self loop: coef = dinv[i]*1*dinv[i]
        float2 hv = unpack_h2(H2[(size_t)node * 64 + lane]);
        float cs = di * di;
        acc.x = cs * hv.x; acc.y = cs * hv.y;
    }
    int e = rowptr[node], eend = rowptr[node + 1];
    for (; e + 4 <= eend; e += 4) {
        u32 e0 = edat[e], e1 = edat[e + 1], e2 = edat[e + 2], e3 = edat[e + 3];
        u32 r0 = H2[(size_t)edge_src(e0) * 64 + lane];
        u32 r1 = H2[(size_t)edge_src(e1) * 64 + lane];
        u32 r2 = H2[(size_t)edge_src(e2) * 64 + lane];
        u32 r3 = H2[(size_t)edge_src(e3) * 64 + lane];
        float2 v0 = unpack_h2(r0), v1 = unpack_h2(r1);
        float2 v2 = unpack_h2(r2), v3 = unpack_h2(r3);
        float c0 = edge_coef(e0), c1 = edge_coef(e1);
        float c2 = edge_coef(e2), c3 = edge_coef(e3);
        acc.x += c0 * v0.x; acc.y += c0 * v0.y;
        acc.x += c1 * v1.x; acc.y += c1 * v1.y;
        acc.x += c2 * v2.x; acc.y += c2 * v2.y;
        acc.x += c3 * v3.x; acc.y += c3 * v3.y;
    }
    for (; e < eend; ++e) {
        u32 ed = edat[e];
        float c = edge_coef(ed);
        float2 v = unpack_h2(H2[(size_t)edge_src(ed) * 64 + lane]);
        acc.x += c * v.x; acc.y += c * v.y;
    }
    acc.x += bias[lane * 2];
    acc.y += bias[lane * 2 + 1];

    float ss = acc.x * acc.x + acc.y * acc.y;
#pragma unroll
    for (int off = 32; off >= 1; off >>= 1) ss += __shfl_xor(ss, off, 64);
    float n = sqrtf(ss);
    float inv = 1.0f / fmaxf(n, 1e-12f);
    float ox = fmaxf(acc.x * inv, 0.0f);
    float oy = fmaxf(acc.y * inv, 0.0f);
    out[(size_t)node * 64 + lane] = pack_h2(ox, oy);
}

// ---------- final linear: concat(o1,o2,o3)[fp16] @ Wlin, light-shuffle reduce
__global__ __launch_bounds__(256)
void k_final(const u32* __restrict__ o1, const u32* __restrict__ o2,
             const u32* __restrict__ o3, const float* __restrict__ Wlin,
             const float* __restrict__ blin, float* __restrict__ out) {
    __shared__ float Wt[C_OUT][384];        // transposed: Wt[c][f]
    __shared__ float part[4][8][C_OUT];     // wave, lane-group, class
    __shared__ float bl[C_OUT];
    int t = threadIdx.x;
    for (int i = t; i < 384 * C_OUT; i += 256) {
        int f = i / C_OUT, c = i % C_OUT;
        Wt[c][f] = Wlin[i];
    }
    if (t < C_OUT) bl[t] = blin[t];
    __syncthreads();

    int wid = t >> 6, lane = t & 63;
    int node = blockIdx.x * 4 + wid;        // grid exact: 12500*4 = 50000

    float2 va = unpack_h2(o1[(size_t)node * 64 + lane]);
    float2 vb = unpack_h2(o2[(size_t)node * 64 + lane]);
    float2 vc = unpack_h2(o3[(size_t)node * 64 + lane]);
    int f0 = lane * 2;

    float acc[C_OUT];
#pragma unroll
    for (int c = 0; c < C_OUT; ++c) {
        acc[c] = va.x * Wt[c][f0]       + va.y * Wt[c][f0 + 1]
               + vb.x * Wt[c][128 + f0] + vb.y * Wt[c][129 + f0]
               + vc.x * Wt[c][256 + f0] + vc.y * Wt[c][257 + f0];
    }
    // 3 shuffle rounds: lane i ends with sum over {j : j == i mod 8}
#pragma unroll
    for (int off = 32; off >= 8; off >>= 1)
#pragma unroll
        for (int c = 0; c < C_OUT; ++c) acc[c] += __shfl_xor(acc[c], off, 64);

    if (lane < 8) {
#pragma unroll
        for (int c = 0; c < C_OUT; ++c) part[wid][lane][c] = acc[c];
    }
    __syncthreads();
    if (t < 4 * C_OUT) {
        int n = t / C_OUT, cc = t % C_OUT;
        float s = 0.f;
#pragma unroll
        for (int l = 0; l < 8; ++l) s += part[n][l][cc];
        out[(size_t)(blockIdx.x * 4 + n) * C_OUT + cc] = s + bl[cc];
    }
}

// -------------------------------------------------------------------- launch
extern "C" void kernel_launch(void* const* d_in, const int* in_sizes, int n_in,
                              void* d_out, int out_size, void* d_ws, size_t ws_size,
                              hipStream_t stream) {
    const float* x  = (const float*)d_in[0];
    const int*   ei = (const int*)d_in[1];
    const float* ew = (const float*)d_in[2];
    const float* W1 = (const float*)d_in[3];
    const float* b1 = (const float*)d_in[4];
    const float* W2 = (const float*)d_in[5];
    const float* b2 = (const float*)d_in[6];
    const float* W3 = (const float*)d_in[7];
    const float* b3 = (const float*)d_in[8];
    const float* Wl = (const float*)d_in[9];
    const float* bl = (const float*)d_in[10];
    float* out = (float*)d_out;

    const int* srcI = ei;             // edge_index[0]
    const int* dstI = ei + N_EDGES;   // edge_index[1]

    char* p = (char*)d_ws;
    auto alloc = [&](size_t bytes) {
        char* r = p;
        p += (bytes + 255) & ~(size_t)255;
        return r;
    };
    u64*   hist   = (u64*)  alloc((size_t)N_NODES * 8);
    float* dinv   = (float*)alloc((size_t)N_NODES * 4);
    int*   cursor = (int*)  alloc((size_t)N_NODES * 4);
    int*   rowptr = (int*)  alloc((size_t)(N_NODES + 1) * 4);
    int*   bsum   = (int*)  alloc((size_t)NBLK * 4);
    u32*   edat   = (u32*)  alloc((size_t)N_EDGES * 4);
    u16*   h      = (u16*)  alloc((size_t)N_NODES * FDIM * 2);
    u32*   o1     = (u32*)  alloc((size_t)N_NODES * 64 * 4);   // fp16-packed
    u32*   o2     = (u32*)  alloc((size_t)N_NODES * 64 * 4);
    u32*   o3     = (u32*)  alloc((size_t)N_NODES * 64 * 4);

    k_init   <<<NBLK, 256, 0, stream>>>(hist);
    k_hist   <<<(N_EDGES + 255) / 256, 256, 0, stream>>>(dstI, ew, hist);
    k_scan1  <<<NBLK, 256, 0, stream>>>(hist, bsum);
    k_scan2  <<<1, 256, 0, stream>>>(bsum);
    k_scan3  <<<NBLK, 256, 0, stream>>>(hist, bsum, dinv, cursor, rowptr);
    k_scatter<<<(N_EDGES + 255) / 256, 256, 0, stream>>>(srcI, dstI, ew, dinv, cursor, edat);

    u32* outs[3] = {o1, o2, o3};
    const float* bvecs[3] = {b1, b2, b3};

    // layer 1: fp32 input x
    k_gemm<float><<<(N_NODES + 63) / 64, 256, 0, stream>>>(x, W1, h);
    k_agg<<<N_NODES / 4, 256, 0, stream>>>(h, rowptr, edat, dinv, bvecs[0], outs[0]);
    // layers 2,3: fp16 input
    k_gemm<u16><<<(N_NODES + 63) / 64, 256, 0, stream>>>((const u16*)outs[0], W2, h);
    k_agg<<<N_NODES / 4, 256, 0, stream>>>(h, rowptr, edat, dinv, bvecs[1], outs[1]);
    k_gemm<u16><<<(N_NODES + 63) / 64, 256, 0, stream>>>((const u16*)outs[1], W3, h);
    k_agg<<<N_NODES / 4, 256, 0, stream>>>(h, rowptr, edat, dinv, bvecs[2], outs[2]);

    k_final<<<N_NODES / 4, 256, 0, stream>>>(o1, o2, o3, Wl, bl, out);
}

// Round 14
// 494.335 us; speedup vs baseline: 2.0511x; 1.1985x over previous
//
#include <hip/hip_runtime.h>
#include <hip/hip_fp16.h>

#define N_NODES 50000
#define N_EDGES 1600000
#define FDIM    128
#define C_OUT   10

#define EBLK   8192
#define PBLK   ((N_EDGES + EBLK - 1) / EBLK)      // 196
#define BSHIFT 7
#define BNODES 128
#define NB     ((N_NODES + BNODES - 1) / BNODES)  // 391

typedef unsigned long long u64;
typedef unsigned int u32;
typedef unsigned short u16;

__device__ __forceinline__ u32 pack_h2(float a, float b) {
    __half2 h = __floats2half2_rn(a, b);
    return *(u32*)&h;
}
__device__ __forceinline__ float2 unpack_h2(u32 u) {
    __half2 h = *(__half2*)&u;
    return __half22float2(h);
}
// edge record: bits[31:15] = src (17b), bits[14:0] = fp16(w) (sign 0, w in (0,1))
__device__ __forceinline__ u32 pack_edge(int s, float w) {
    __half h = __float2half_rn(w);
    u16 hb = *(u16*)&h;
    return ((u32)s << 15) | (u32)hb;
}
__device__ __forceinline__ int edge_src(u32 u) { return (int)(u >> 15); }
__device__ __forceinline__ float edge_w(u32 u) {
    u16 hb = (u16)(u & 0x7FFFu);
    __half h = *(__half*)&hb;
    return __half2float(h);
}
// staging record: bits[62:56]=dstLocal(7), bits[48:32]=src(17), bits[31:0]=fp32 w
__device__ __forceinline__ u64 pack_stage(int dl, int s, float w) {
    return ((u64)(u32)dl << 56) | ((u64)(u32)s << 32) | (u64)__float_as_uint(w);
}

// ----------------------------------------------------------------- zero
__global__ void k_zero(u32* __restrict__ bucketCnt) {
    int t = threadIdx.x;
    if (t < NB) bucketCnt[t] = 0;
}

// ---------------------------- bucket histogram (LDS-staged, few global atomics)
__global__ __launch_bounds__(256)
void k_bhist(const int* __restrict__ dst, u32* __restrict__ bucketCnt) {
    __shared__ u32 cnt[NB];
    int t = threadIdx.x;
    for (int i = t; i < NB; i += 256) cnt[i] = 0;
    __syncthreads();
    int e0 = blockIdx.x * EBLK;
    for (int i = t; i < EBLK; i += 256) {
        int e = e0 + i;
        if (e < N_EDGES) atomicAdd(&cnt[dst[e] >> BSHIFT], 1u);
    }
    __syncthreads();
    for (int i = t; i < NB; i += 256)
        if (cnt[i]) atomicAdd(&bucketCnt[i], cnt[i]);
}

// ------------------- scan bucket counts -> bucketBase / bucketCursor (1 block)
__global__ __launch_bounds__(512)
void k_bscan(const u32* __restrict__ bucketCnt, int* __restrict__ bucketBase,
             int* __restrict__ bucketCursor, int* __restrict__ rowptr) {
    int t = threadIdx.x, lane = t & 63, wv = t >> 6;
    int v = (t < NB) ? (int)bucketCnt[t] : 0;
    int x = v;
#pragma unroll
    for (int off = 1; off < 64; off <<= 1) {
        int y = __shfl_up(x, off, 64);
        if (lane >= off) x += y;
    }
    __shared__ int wt[8];
    if (lane == 63) wt[wv] = x;
    __syncthreads();
    int add = 0;
    for (int j = 0; j < wv; ++j) add += wt[j];
    if (t < NB) {
        int excl = add + x - v;
        bucketBase[t]   = excl;
        bucketCursor[t] = excl;
    }
    if (t == 0) {
        bucketBase[NB]     = N_EDGES;
        rowptr[N_NODES]    = N_EDGES;
    }
}

// ---------------- partition edges into bucket streams (write-combined staging)
__global__ __launch_bounds__(256)
void k_part(const int* __restrict__ src, const int* __restrict__ dst,
            const float* __restrict__ w, int* __restrict__ bucketCursor,
            u64* __restrict__ staging) {
    __shared__ u32 cnt[NB];
    __shared__ u32 base[NB];
    __shared__ u32 lcur[NB];
    int t = threadIdx.x;
    for (int i = t; i < NB; i += 256) cnt[i] = 0;
    __syncthreads();
    int e0 = blockIdx.x * EBLK;
    for (int i = t; i < EBLK; i += 256) {
        int e = e0 + i;
        if (e < N_EDGES) atomicAdd(&cnt[dst[e] >> BSHIFT], 1u);
    }
    __syncthreads();
    for (int i = t; i < NB; i += 256) {
        u32 c = cnt[i];
        lcur[i] = 0;
        if (c) base[i] = (u32)atomicAdd(&bucketCursor[i], (int)c);
    }
    __syncthreads();
    for (int i = t; i < EBLK; i += 256) {
        int e = e0 + i;
        if (e >= N_EDGES) continue;
        int d = dst[e];
        int b = d >> BSHIFT;
        u32 pos = base[b] + atomicAdd(&lcur[b], 1u);
        staging[pos] = pack_stage(d & (BNODES - 1), src[e], w[e]);
    }
}

// ------ per-bucket build: deg/dinv + rowptr + locally-sorted final edge array
__global__ __launch_bounds__(256)
void k_build(const u64* __restrict__ staging, const int* __restrict__ bucketBase,
             int* __restrict__ rowptr, float* __restrict__ dinv,
             u32* __restrict__ edat) {
    __shared__ u32 cnt[BNODES];
    __shared__ u32 wfx[BNODES];
    __shared__ int rowl[BNODES];
    __shared__ u32 cur[BNODES];
    __shared__ int wt[2];
    int t = threadIdx.x;
    int b = blockIdx.x;
    int lo = b * BNODES;
    int nn = min(BNODES, N_NODES - lo);
    int segBase = bucketBase[b], segEnd = bucketBase[b + 1];

    if (t < BNODES) { cnt[t] = 0; wfx[t] = 0; }
    __syncthreads();
    for (int i = segBase + t; i < segEnd; i += 256) {
        u64 r = staging[i];
        int d = (int)(r >> 56);
        float wv = __uint_as_float((u32)r);
        atomicAdd(&cnt[d], 1u);
        atomicAdd(&wfx[d], (u32)(wv * 1048576.0f + 0.5f));   // 2^20 fixed point
    }
    __syncthreads();
    int v = 0, x = 0, lane = t & 63, wv2 = t >> 6;
    if (t < BNODES) {
        v = (int)cnt[t]; x = v;
#pragma unroll
        for (int off = 1; off < 64; off <<= 1) {
            int y = __shfl_up(x, off, 64);
            if (lane >= off) x += y;
        }
        if (lane == 63) wt[wv2] = x;
    }
    __syncthreads();
    if (t < BNODES) {
        int add = (wv2 == 1) ? wt[0] : 0;
        int ro = add + x - v;                 // exclusive local offset
        rowl[t] = ro;
        cur[t]  = 0;
        if (t < nn) {
            rowptr[lo + t] = segBase + ro;
            float deg = 1.0f + (float)wfx[t] * (1.0f / 1048576.0f);
            dinv[lo + t] = rsqrtf(deg);
        }
    }
    __syncthreads();
    for (int i = segBase + t; i < segEnd; i += 256) {
        u64 r = staging[i];
        int d = (int)(r >> 56);
        int s = (int)((r >> 32) & 0x1FFFF);
        float wf = __uint_as_float((u32)r);
        u32 slot = (u32)rowl[d] + atomicAdd(&cur[d], 1u);
        edat[segBase + slot] = pack_edge(s, wf);
    }
}

// ---- fp32-accum GEMM  H' = dinv * (X @ W), stored fp16; X fp32|fp16
template<typename TIN>
__global__ __launch_bounds__(256)
void k_gemm(const TIN* __restrict__ X, const float* __restrict__ W,
            const float* __restrict__ dinv, u16* __restrict__ H) {
    __shared__ float Wl[64][128];   // 32 KB
    __shared__ float Xl[64][68];    // pad 64->68
    int t = threadIdx.x;
    int rb = blockIdx.x * 64;
    int colb = (t & 31) * 4;
    int rg = t >> 5;

    float acc[8][4] = {};

    for (int k0 = 0; k0 < 128; k0 += 64) {
        {
            const float4* Wg = (const float4*)(W + k0 * 128);
            float4* Ws = (float4*)&Wl[0][0];
#pragma unroll
            for (int j = 0; j < 8; ++j) Ws[t + 256 * j] = Wg[t + 256 * j];
        }
        {
#pragma unroll
            for (int j = 0; j < 4; ++j) {
                int idx = t + 256 * j;
                int r = idx >> 4;
                int c4 = (idx & 15) * 4;
                int row = rb + r;
                float4 vv = make_float4(0.f, 0.f, 0.f, 0.f);
                if (row < N_NODES) {
                    if constexpr (sizeof(TIN) == 4) {
                        vv = *(const float4*)(X + (size_t)row * FDIM + k0 + c4);
                    } else {
                        uint2 pv = *(const uint2*)(X + (size_t)row * FDIM + k0 + c4);
                        float2 lov = unpack_h2(pv.x), hiv = unpack_h2(pv.y);
                        vv = make_float4(lov.x, lov.y, hiv.x, hiv.y);
                    }
                }
                *(float4*)&Xl[r][c4] = vv;
            }
        }
        __syncthreads();
#pragma unroll
        for (int k = 0; k < 64; k += 4) {
            float4 wv0 = *(const float4*)&Wl[k + 0][colb];
            float4 wv1 = *(const float4*)&Wl[k + 1][colb];
            float4 wv2 = *(const float4*)&Wl[k + 2][colb];
            float4 wv3 = *(const float4*)&Wl[k + 3][colb];
#pragma unroll
            for (int r = 0; r < 8; ++r) {
                float4 xv = *(const float4*)&Xl[rg * 8 + r][k];
                acc[r][0] += xv.x * wv0.x; acc[r][1] += xv.x * wv0.y;
                acc[r][2] += xv.x * wv0.z; acc[r][3] += xv.x * wv0.w;
                acc[r][0] += xv.y * wv1.x; acc[r][1] += xv.y * wv1.y;
                acc[r][2] += xv.y * wv1.z; acc[r][3] += xv.y * wv1.w;
                acc[r][0] += xv.z * wv2.x; acc[r][1] += xv.z * wv2.y;
                acc[r][2] += xv.z * wv2.z; acc[r][3] += xv.z * wv2.w;
                acc[r][0] += xv.w * wv3.x; acc[r][1] += xv.w * wv3.y;
                acc[r][2] += xv.w * wv3.z; acc[r][3] += xv.w * wv3.w;
            }
        }
        __syncthreads();
    }
#pragma unroll
    for (int r = 0; r < 8; ++r) {
        int row = rb + rg * 8 + r;
        if (row < N_NODES) {
            float di = dinv[row];
            uint2 pv;
            pv.x = pack_h2(acc[r][0] * di, acc[r][1] * di);
            pv.y = pack_h2(acc[r][2] * di, acc[r][3] * di);
            *(uint2*)(H + (size_t)row * FDIM + colb) = pv;
        }
    }
}

// --- aggregation: out = dinv[d]*(sum w*h'[s] + h'[d]) + bias; L2norm+ReLU
__global__ __launch_bounds__(256)
void k_agg(const u16* __restrict__ H, const int* __restrict__ rowptr,
           const u32* __restrict__ edat, const float* __restrict__ dinv,
           const float* __restrict__ bias, u32* __restrict__ out) {
    int wid  = threadIdx.x >> 6;
    int lane = threadIdx.x & 63;
    int node = blockIdx.x * 4 + wid;
    if (node >= N_NODES) return;

    const u32* H2 = (const u32*)H;   // 2 fp16 per u32; row stride 64 u32
    float di = dinv[node];
    float2 acc = unpack_h2(H2[(size_t)node * 64 + lane]);   // self: h'[node]

    int e = rowptr[node], eend = rowptr[node + 1];
    for (; e + 4 <= eend; e += 4) {
        u32 e0 = edat[e], e1 = edat[e + 1], e2 = edat[e + 2], e3 = edat[e + 3];
        u32 r0 = H2[(size_t)edge_src(e0) * 64 + lane];
        u32 r1 = H2[(size_t)edge_src(e1) * 64 + lane];
        u32 r2 = H2[(size_t)edge_src(e2) * 64 + lane];
        u32 r3 = H2[(size_t)edge_src(e3) * 64 + lane];
        float2 v0 = unpack_h2(r0), v1 = unpack_h2(r1);
        float2 v2 = unpack_h2(r2), v3 = unpack_h2(r3);
        float c0 = edge_w(e0), c1 = edge_w(e1);
        float c2 = edge_w(e2), c3 = edge_w(e3);
        acc.x += c0 * v0.x; acc.y += c0 * v0.y;
        acc.x += c1 * v1.x; acc.y += c1 * v1.y;
        acc.x += c2 * v2.x; acc.y += c2 * v2.y;
        acc.x += c3 * v3.x; acc.y += c3 * v3.y;
    }
    for (; e < eend; ++e) {
        u32 ed = edat[e];
        float c = edge_w(ed);
        float2 vv = unpack_h2(H2[(size_t)edge_src(ed) * 64 + lane]);
        acc.x += c * vv.x; acc.y += c * vv.y;
    }
    acc.x = acc.x * di + bias[lane * 2];
    acc.y = acc.y * di + bias[lane * 2 + 1];

    float ss = acc.x * acc.x + acc.y * acc.y;
#pragma unroll
    for (int off = 32; off >= 1; off >>= 1) ss += __shfl_xor(ss, off, 64);
    float n = sqrtf(ss);
    float inv = 1.0f / fmaxf(n, 1e-12f);
    float ox = fmaxf(acc.x * inv, 0.0f);
    float oy = fmaxf(acc.y * inv, 0.0f);
    out[(size_t)node * 64 + lane] = pack_h2(ox, oy);
}

// ---------- final linear: concat(o1,o2,o3)[fp16] @ Wlin, light-shuffle reduce
__global__ __launch_bounds__(256)
void k_final(const u32* __restrict__ o1, const u32* __restrict__ o2,
             const u32* __restrict__ o3, const float* __restrict__ Wlin,
             const float* __restrict__ blin, float* __restrict__ out) {
    __shared__ float Wt[C_OUT][384];
    __shared__ float part[4][8][C_OUT];
    __shared__ float bl[C_OUT];
    int t = threadIdx.x;
    for (int i = t; i < 384 * C_OUT; i += 256) {
        int f = i / C_OUT, c = i % C_OUT;
        Wt[c][f] = Wlin[i];
    }
    if (t < C_OUT) bl[t] = blin[t];
    __syncthreads();

    int wid = t >> 6, lane = t & 63;
    int node = blockIdx.x * 4 + wid;

    float2 va = unpack_h2(o1[(size_t)node * 64 + lane]);
    float2 vb = unpack_h2(o2[(size_t)node * 64 + lane]);
    float2 vc = unpack_h2(o3[(size_t)node * 64 + lane]);
    int f0 = lane * 2;

    float acc[C_OUT];
#pragma unroll
    for (int c = 0; c < C_OUT; ++c) {
        acc[c] = va.x * Wt[c][f0]       + va.y * Wt[c][f0 + 1]
               + vb.x * Wt[c][128 + f0] + vb.y * Wt[c][129 + f0]
               + vc.x * Wt[c][256 + f0] + vc.y * Wt[c][257 + f0];
    }
#pragma unroll
    for (int off = 32; off >= 8; off >>= 1)
#pragma unroll
        for (int c = 0; c < C_OUT; ++c) acc[c] += __shfl_xor(acc[c], off, 64);

    if (lane < 8) {
#pragma unroll
        for (int c = 0; c < C_OUT; ++c) part[wid][lane][c] = acc[c];
    }
    __syncthreads();
    if (t < 4 * C_OUT) {
        int n = t / C_OUT, cc = t % C_OUT;
        float s = 0.f;
#pragma unroll
        for (int l = 0; l < 8; ++l) s += part[n][l][cc];
        out[(size_t)(blockIdx.x * 4 + n) * C_OUT + cc] = s + bl[cc];
    }
}

// -------------------------------------------------------------------- launch
extern "C" void kernel_launch(void* const* d_in, const int* in_sizes, int n_in,
                              void* d_out, int out_size, void* d_ws, size_t ws_size,
                              hipStream_t stream) {
    const float* x  = (const float*)d_in[0];
    const int*   ei = (const int*)d_in[1];
    const float* ew = (const float*)d_in[2];
    const float* W1 = (const float*)d_in[3];
    const float* b1 = (const float*)d_in[4];
    const float* W2 = (const float*)d_in[5];
    const float* b2 = (const float*)d_in[6];
    const float* W3 = (const float*)d_in[7];
    const float* b3 = (const float*)d_in[8];
    const float* Wl = (const float*)d_in[9];
    const float* bl = (const float*)d_in[10];
    float* out = (float*)d_out;

    const int* srcI = ei;             // edge_index[0]
    const int* dstI = ei + N_EDGES;   // edge_index[1]

    char* p = (char*)d_ws;
    auto alloc = [&](size_t bytes) {
        char* r = p;
        p += (bytes + 255) & ~(size_t)255;
        return r;
    };
    u32*   bucketCnt  = (u32*)alloc((size_t)NB * 4);
    int*   bucketBase = (int*)alloc((size_t)(NB + 1) * 4);
    int*   bucketCur  = (int*)alloc((size_t)NB * 4);
    int*   rowptr     = (int*)alloc((size_t)(N_NODES + 1) * 4);
    float* dinv       = (float*)alloc((size_t)N_NODES * 4);
    u64*   staging    = (u64*)alloc((size_t)N_EDGES * 8);
    u32*   edat       = (u32*)alloc((size_t)N_EDGES * 4);
    u16*   h          = (u16*)alloc((size_t)N_NODES * FDIM * 2);
    u32*   o1         = (u32*)alloc((size_t)N_NODES * 64 * 4);
    u32*   o2         = (u32*)alloc((size_t)N_NODES * 64 * 4);
    u32*   o3         = (u32*)alloc((size_t)N_NODES * 64 * 4);

    k_zero <<<1, 512, 0, stream>>>(bucketCnt);
    k_bhist<<<PBLK, 256, 0, stream>>>(dstI, bucketCnt);
    k_bscan<<<1, 512, 0, stream>>>(bucketCnt, bucketBase, bucketCur, rowptr);
    k_part <<<PBLK, 256, 0, stream>>>(srcI, dstI, ew, bucketCur, staging);
    k_build<<<NB, 256, 0, stream>>>(staging, bucketBase, rowptr, dinv, edat);

    // layer 1: fp32 input x
    k_gemm<float><<<(N_NODES + 63) / 64, 256, 0, stream>>>(x, W1, dinv, h);
    k_agg<<<N_NODES / 4, 256, 0, stream>>>(h, rowptr, edat, dinv, b1, o1);
    // layers 2,3: fp16 input
    k_gemm<u16><<<(N_NODES + 63) / 64, 256, 0, stream>>>((const u16*)o1, W2, dinv, h);
    k_agg<<<N_NODES / 4, 256, 0, stream>>>(h, rowptr, edat, dinv, b2, o2);
    k_gemm<u16><<<(N_NODES + 63) / 64, 256, 0, stream>>>((const u16*)o2, W3, dinv, h);
    k_agg<<<N_NODES / 4, 256, 0, stream>>>(h, rowptr, edat, dinv, b3, o3);

    k_final<<<N_NODES / 4, 256, 0, stream>>>(o1, o2, o3, Wl, bl, out);
}